// Round 2
// baseline (277.298 us; speedup 1.0000x reference)
//
#include <hip/hip_runtime.h>
#include <hip/hip_bf16.h>

typedef __bf16 bf16x8 __attribute__((ext_vector_type(8)));
typedef float f32x4 __attribute__((ext_vector_type(4)));
typedef unsigned short us8 __attribute__((ext_vector_type(8)));

#define E_ 640
#define CD_ 768
#define B_ 32
#define SQ_ 1024
#define SKV_ 77
#define H_ 8
#define DH_ 80

__device__ __forceinline__ float b2f(unsigned short u) {
    unsigned int x = ((unsigned int)u) << 16;
    return __builtin_bit_cast(float, x);
}
__device__ __forceinline__ unsigned short f2b(float f) {
    unsigned int x = __builtin_bit_cast(unsigned int, f);
    x += 0x7fffu + ((x >> 16) & 1u);   // RNE
    return (unsigned short)(x >> 16);
}
__device__ __forceinline__ bf16x8 lv8(const unsigned short* p) {
    return __builtin_bit_cast(bf16x8, *reinterpret_cast<const us8*>(p));
}
__device__ __forceinline__ bf16x8 zero8() {
    us8 z = {0,0,0,0,0,0,0,0};
    return __builtin_bit_cast(bf16x8, z);
}

// ---------------- transpose+cast: in f32 [K][N] -> out bf16 [N][K] ----------------
__global__ __launch_bounds__(256) void transpose_kernel(
    const float* __restrict__ in, unsigned short* __restrict__ out,
    int K, int N)
{
    __shared__ unsigned short t[32][33];
    const int tx = threadIdx.x & 31, ty = threadIdx.x >> 5;
    const int n0 = blockIdx.x * 32, k0 = blockIdx.y * 32;
#pragma unroll
    for (int i = 0; i < 4; ++i)
        t[ty + 8*i][tx] = f2b(in[(size_t)(k0 + ty + 8*i) * N + n0 + tx]);
    __syncthreads();
#pragma unroll
    for (int i = 0; i < 4; ++i)
        out[(size_t)(n0 + ty + 8*i) * K + k0 + tx] = t[tx][ty + 8*i];
}

// ---------------- GEMM: C[M][640] = A[M][K] @ W[K][640] + bias ----------------
// Wt is W transposed+cast: [640][K] bf16. bias is f32. 128x128 tile, 4 waves.
// AF32: A is fp32 (else bf16). CF32: C store fp32 (else bf16).
template<bool AF32, bool CF32>
__global__ __launch_bounds__(256) void gemm_kernel(
    const void* __restrict__ Ap,
    const unsigned short* __restrict__ Wt,
    const float* __restrict__ bias,
    void* __restrict__ Cp,
    int M, int K)
{
    __shared__ __align__(16) unsigned short As[128 * 40];
    __shared__ __align__(16) unsigned short Ws[128 * 40];
    const int tid = threadIdx.x;
    const int lane = tid & 63;
    const int wave = tid >> 6;
    const int wr = (wave >> 1) * 64, wc = (wave & 1) * 64;
    const int m0 = blockIdx.x * 128;
    const int n0 = blockIdx.y * 128;
    const int l15 = lane & 15, l4 = lane >> 4;

    f32x4 acc[4][4];
#pragma unroll
    for (int m = 0; m < 4; ++m)
#pragma unroll
        for (int n = 0; n < 4; ++n)
#pragma unroll
            for (int i = 0; i < 4; ++i) acc[m][n][i] = 0.f;

    const int nk = K >> 5;
    for (int kt = 0; kt < nk; ++kt) {
        const int k0 = kt << 5;
#pragma unroll
        for (int j = 0; j < 2; ++j) {
            int idx = tid + j * 256;
            int row = idx >> 2, seg = idx & 3;
            int gr = m0 + row; if (gr >= M) gr = M - 1;
            if constexpr (AF32) {
                const float* src = (const float*)Ap + (size_t)gr * K + k0 + seg * 8;
                f32x4 f0 = *reinterpret_cast<const f32x4*>(src);
                f32x4 f1 = *reinterpret_cast<const f32x4*>(src + 4);
                us8 v;
                v[0]=f2b(f0[0]); v[1]=f2b(f0[1]); v[2]=f2b(f0[2]); v[3]=f2b(f0[3]);
                v[4]=f2b(f1[0]); v[5]=f2b(f1[1]); v[6]=f2b(f1[2]); v[7]=f2b(f1[3]);
                *reinterpret_cast<us8*>(&As[row * 40 + seg * 8]) = v;
            } else {
                *reinterpret_cast<us8*>(&As[row * 40 + seg * 8]) =
                    *reinterpret_cast<const us8*>((const unsigned short*)Ap + (size_t)gr * K + k0 + seg * 8);
            }
            *reinterpret_cast<us8*>(&Ws[row * 40 + seg * 8]) =
                *reinterpret_cast<const us8*>(&Wt[(size_t)(n0 + row) * K + k0 + seg * 8]);
        }
        __syncthreads();
        bf16x8 a[4], b[4];
#pragma unroll
        for (int m = 0; m < 4; ++m)
            a[m] = lv8(&As[(wr + m * 16 + l15) * 40 + l4 * 8]);
#pragma unroll
        for (int n = 0; n < 4; ++n)
            b[n] = lv8(&Ws[(wc + n * 16 + l15) * 40 + l4 * 8]);
#pragma unroll
        for (int m = 0; m < 4; ++m)
#pragma unroll
            for (int n = 0; n < 4; ++n)
                acc[m][n] = __builtin_amdgcn_mfma_f32_16x16x32_bf16(a[m], b[n], acc[m][n], 0, 0, 0);
        __syncthreads();
    }
#pragma unroll
    for (int n = 0; n < 4; ++n) {
        const int col = n0 + wc + n * 16 + l15;
        const float bv = bias[col];
#pragma unroll
        for (int m = 0; m < 4; ++m) {
            const int rbase = m0 + wr + m * 16 + l4 * 4;
#pragma unroll
            for (int i = 0; i < 4; ++i) {
                const int r = rbase + i;
                if (r < M) {
                    if constexpr (CF32)
                        ((float*)Cp)[(size_t)r * E_ + col] = acc[m][n][i] + bv;
                    else
                        ((unsigned short*)Cp)[(size_t)r * E_ + col] = f2b(acc[m][n][i] + bv);
                }
            }
        }
    }
}

// ---------------- attention: per (128 q-rows, head, batch), all bf16 ws ----------------
__global__ __launch_bounds__(128) void attn_kernel(
    const unsigned short* __restrict__ Q,
    const unsigned short* __restrict__ Kp,
    const unsigned short* __restrict__ Vp,
    unsigned short* __restrict__ Oa)
{
    __shared__ __align__(16) unsigned short Kl[80 * 104];   // [kv][d] d padded to 96
    __shared__ __align__(16) unsigned short Vt[80 * 104];   // [d][kv] kv padded to 96
    __shared__ __align__(16) unsigned short Pl[2][64 * 104];// per-wave [q][kv]
    const int tid = threadIdx.x, lane = tid & 63, wave = tid >> 6;
    const int l15 = lane & 15, l4 = lane >> 4;
    const int qb = blockIdx.x * 128, h = blockIdx.y, b = blockIdx.z;
    const size_t kvbase = (size_t)b * SKV_ * E_ + (size_t)h * DH_;

    for (int idx = tid; idx < 160; idx += 128) {            // K cols 80..95
        int row = idx >> 1, seg = idx & 1;
        *reinterpret_cast<us8*>(&Kl[row * 104 + 80 + seg * 8]) = (us8){0,0,0,0,0,0,0,0};
    }
    for (int idx = tid; idx < 30; idx += 128) {             // K rows 77..79 cols 0..79
        int row = 77 + idx / 10, seg = idx % 10;
        *reinterpret_cast<us8*>(&Kl[row * 104 + seg * 8]) = (us8){0,0,0,0,0,0,0,0};
    }
    for (int idx = tid; idx < 80 * 19; idx += 128) {        // Vt cols 77..95
        int row = idx / 19, c = 77 + idx % 19;
        Vt[row * 104 + c] = 0;
    }
    for (int idx = tid; idx < 256; idx += 128) {            // P cols 80..95, both waves
        int w = idx >> 7, rem = idx & 127;
        int row = rem >> 1, seg = rem & 1;
        *reinterpret_cast<us8*>(&Pl[w][row * 104 + 80 + seg * 8]) = (us8){0,0,0,0,0,0,0,0};
    }
    for (int idx = tid; idx < 770; idx += 128) {            // stage K rows
        int kv = idx / 10, seg = idx % 10;
        *reinterpret_cast<us8*>(&Kl[kv * 104 + seg * 8]) =
            *reinterpret_cast<const us8*>(&Kp[kvbase + (size_t)kv * E_ + seg * 8]);
    }
    for (int idx = tid; idx < 77 * 80; idx += 128) {        // stage V transposed
        int kv = idx / 80, d = idx % 80;
        Vt[d * 104 + kv] = Vp[kvbase + (size_t)kv * E_ + d];
    }
    __syncthreads();

    f32x4 accS[4][5];
#pragma unroll
    for (int m = 0; m < 4; ++m)
#pragma unroll
        for (int n = 0; n < 5; ++n)
#pragma unroll
            for (int i = 0; i < 4; ++i) accS[m][n][i] = 0.f;

    const size_t qrow0 = (size_t)b * SQ_ + qb + wave * 64;
#pragma unroll
    for (int ks = 0; ks < 3; ++ks) {
        bf16x8 aq[4];
        const int d = ks * 32 + l4 * 8;
#pragma unroll
        for (int m = 0; m < 4; ++m) {
            if (d < 80)
                aq[m] = lv8(&Q[(qrow0 + m * 16 + l15) * E_ + h * DH_ + d]);
            else
                aq[m] = zero8();
        }
#pragma unroll
        for (int n = 0; n < 5; ++n) {
            bf16x8 bk = lv8(&Kl[(n * 16 + l15) * 104 + ks * 32 + l4 * 8]);
#pragma unroll
            for (int m = 0; m < 4; ++m)
                accS[m][n] = __builtin_amdgcn_mfma_f32_16x16x32_bf16(aq[m], bk, accS[m][n], 0, 0, 0);
        }
    }

    const float scale = 0.11180339887498949f; // 1/sqrt(80)
    float rs[4][4];
#pragma unroll
    for (int m = 0; m < 4; ++m) {
#pragma unroll
        for (int i = 0; i < 4; ++i) {
            float mx = -1e30f;
#pragma unroll
            for (int n = 0; n < 5; ++n) {
                float s = accS[m][n][i] * scale;
                if (n == 4 && l15 >= 13) s = -1e30f;   // kv = 64+l15 >= 77
                accS[m][n][i] = s;
                mx = fmaxf(mx, s);
            }
            mx = fmaxf(mx, __shfl_xor(mx, 1));
            mx = fmaxf(mx, __shfl_xor(mx, 2));
            mx = fmaxf(mx, __shfl_xor(mx, 4));
            mx = fmaxf(mx, __shfl_xor(mx, 8));
            float sum = 0.f;
            const int prow = m * 16 + l4 * 4 + i;
#pragma unroll
            for (int n = 0; n < 5; ++n) {
                float p = __expf(accS[m][n][i] - mx);
                sum += p;
                Pl[wave][prow * 104 + n * 16 + l15] = f2b(p);
            }
            sum += __shfl_xor(sum, 1);
            sum += __shfl_xor(sum, 2);
            sum += __shfl_xor(sum, 4);
            sum += __shfl_xor(sum, 8);
            rs[m][i] = sum;
        }
    }
    __syncthreads();

    f32x4 accO[4][5];
#pragma unroll
    for (int m = 0; m < 4; ++m)
#pragma unroll
        for (int n = 0; n < 5; ++n)
#pragma unroll
            for (int i = 0; i < 4; ++i) accO[m][n][i] = 0.f;
#pragma unroll
    for (int ks = 0; ks < 3; ++ks) {
        bf16x8 ap[4];
#pragma unroll
        for (int m = 0; m < 4; ++m)
            ap[m] = lv8(&Pl[wave][(m * 16 + l15) * 104 + ks * 32 + l4 * 8]);
#pragma unroll
        for (int n = 0; n < 5; ++n) {
            bf16x8 bv = lv8(&Vt[(n * 16 + l15) * 104 + ks * 32 + l4 * 8]);
#pragma unroll
            for (int m = 0; m < 4; ++m)
                accO[m][n] = __builtin_amdgcn_mfma_f32_16x16x32_bf16(ap[m], bv, accO[m][n], 0, 0, 0);
        }
    }
#pragma unroll
    for (int m = 0; m < 4; ++m) {
#pragma unroll
        for (int i = 0; i < 4; ++i) {
            const float inv = 1.f / rs[m][i];
            const size_t row = qrow0 + m * 16 + l4 * 4 + i;
#pragma unroll
            for (int n = 0; n < 5; ++n)
                Oa[row * E_ + h * DH_ + n * 16 + l15] = f2b(accO[m][n][i] * inv);
        }
    }
}

extern "C" void kernel_launch(void* const* d_in, const int* in_sizes, int n_in,
                              void* d_out, int out_size, void* d_ws, size_t ws_size,
                              hipStream_t stream) {
    const float* x  = (const float*)d_in[0];
    const float* y  = (const float*)d_in[1];
    const float* Wq = (const float*)d_in[2];
    const float* bq = (const float*)d_in[3];
    const float* Wk = (const float*)d_in[4];
    const float* bk = (const float*)d_in[5];
    const float* Wv = (const float*)d_in[6];
    const float* bv = (const float*)d_in[7];
    const float* Wo = (const float*)d_in[8];
    const float* bo = (const float*)d_in[9];
    float* out = (float*)d_out;

    char* ws = (char*)d_ws;
    unsigned short* WqT = (unsigned short*)(ws + 0);         //  819200 B
    unsigned short* WkT = (unsigned short*)(ws + 819200);    //  983040 B
    unsigned short* WvT = (unsigned short*)(ws + 1802240);   //  983040 B
    unsigned short* WoT = (unsigned short*)(ws + 2785280);   //  819200 B
    unsigned short* Qb  = (unsigned short*)(ws + 3604480);   // 41943040 B (Q, then attn out in-place)
    unsigned short* Kb  = (unsigned short*)(ws + 45547520);  //  3153920 B
    unsigned short* Vb  = (unsigned short*)(ws + 48701440);  //  3153920 B
    // total: 51,855,360 B

    transpose_kernel<<<dim3(20, 20), 256, 0, stream>>>(Wq, WqT, 640, 640);
    transpose_kernel<<<dim3(20, 24), 256, 0, stream>>>(Wk, WkT, 768, 640);
    transpose_kernel<<<dim3(20, 24), 256, 0, stream>>>(Wv, WvT, 768, 640);
    transpose_kernel<<<dim3(20, 20), 256, 0, stream>>>(Wo, WoT, 640, 640);

    gemm_kernel<true,  false><<<dim3(256, 5), 256, 0, stream>>>(x, WqT, bq, Qb, 32768, 640);
    gemm_kernel<true,  false><<<dim3(20, 5),  256, 0, stream>>>(y, WkT, bk, Kb, 2464, 768);
    gemm_kernel<true,  false><<<dim3(20, 5),  256, 0, stream>>>(y, WvT, bv, Vb, 2464, 768);

    attn_kernel<<<dim3(8, 8, 32), 128, 0, stream>>>(Qb, Kb, Vb, Qb);

    gemm_kernel<false, true><<<dim3(256, 5), 256, 0, stream>>>(Qb, WoT, bo, out, 32768, 640);
}

// Round 3
// 246.333 us; speedup vs baseline: 1.1257x; 1.1257x over previous
//
#include <hip/hip_runtime.h>
#include <hip/hip_bf16.h>

typedef __bf16 bf16x8 __attribute__((ext_vector_type(8)));
typedef float f32x4 __attribute__((ext_vector_type(4)));
typedef unsigned short us8 __attribute__((ext_vector_type(8)));

#define E_ 640
#define CD_ 768
#define B_ 32
#define SQ_ 1024
#define SKV_ 77
#define H_ 8
#define DH_ 80

typedef __attribute__((address_space(3))) unsigned int as3_u32;
typedef __attribute__((address_space(1))) const unsigned int as1_u32;

__device__ __forceinline__ void gload16(const unsigned short* g, unsigned short* l) {
    __builtin_amdgcn_global_load_lds((as1_u32*)g, (as3_u32*)l, 16, 0, 0);
}

__device__ __forceinline__ float b2f(unsigned short u) {
    unsigned int x = ((unsigned int)u) << 16;
    return __builtin_bit_cast(float, x);
}
__device__ __forceinline__ unsigned short f2b(float f) {
    unsigned int x = __builtin_bit_cast(unsigned int, f);
    x += 0x7fffu + ((x >> 16) & 1u);   // RNE
    return (unsigned short)(x >> 16);
}
__device__ __forceinline__ bf16x8 lv8(const unsigned short* p) {
    return __builtin_bit_cast(bf16x8, *reinterpret_cast<const us8*>(p));
}
__device__ __forceinline__ bf16x8 zero8() {
    us8 z = {0,0,0,0,0,0,0,0};
    return __builtin_bit_cast(bf16x8, z);
}
__device__ __forceinline__ us8 cvt8(const float* s) {
    f32x4 f0 = *reinterpret_cast<const f32x4*>(s);
    f32x4 f1 = *reinterpret_cast<const f32x4*>(s + 4);
    us8 v;
    v[0]=f2b(f0[0]); v[1]=f2b(f0[1]); v[2]=f2b(f0[2]); v[3]=f2b(f0[3]);
    v[4]=f2b(f1[0]); v[5]=f2b(f1[1]); v[6]=f2b(f1[2]); v[7]=f2b(f1[3]);
    return v;
}

// ---------------- convert: fp32 -> bf16, 8 elems/thread/iter ----------------
__global__ __launch_bounds__(256) void convert_kernel(
    const float* __restrict__ in, unsigned short* __restrict__ out, long n8)
{
    long i = (long)blockIdx.x * 256 + threadIdx.x;
    const long stride = (long)gridDim.x * 256;
    for (; i < n8; i += stride)
        *reinterpret_cast<us8*>(out + i * 8) = cvt8(in + i * 8);
}

// ---------------- transpose+cast: in f32 [K][N] -> out bf16 [N][K] ----------------
__global__ __launch_bounds__(256) void transpose_kernel(
    const float* __restrict__ in, unsigned short* __restrict__ out,
    int K, int N)
{
    __shared__ unsigned short t[32][33];
    const int tx = threadIdx.x & 31, ty = threadIdx.x >> 5;
    const int n0 = blockIdx.x * 32, k0 = blockIdx.y * 32;
#pragma unroll
    for (int i = 0; i < 4; ++i)
        t[ty + 8*i][tx] = f2b(in[(size_t)(k0 + ty + 8*i) * N + n0 + tx]);
    __syncthreads();
#pragma unroll
    for (int i = 0; i < 4; ++i)
        out[(size_t)(n0 + ty + 8*i) * K + k0 + tx] = t[tx][ty + 8*i];
}

// ---------------- GEMM2: C[M][ldc] = A[M][K] @ Wt^T + bias ----------------
// Wt: [N][K] bf16 (transposed weights). 128x128 tile, BK=32, 4 waves.
// AMODE 0: A bf16, global_load_lds staging (requires M % 128 == 0).
// AMODE 1: A fp32, register-staged with convert (any M, clamped).
// CF32: store fp32 directly; else bf16 via coalesced LDS epilogue.
template<int AMODE, bool CF32>
__global__ __launch_bounds__(256) void gemm2(
    const void* __restrict__ Ap,
    const unsigned short* __restrict__ Wt,
    const float* __restrict__ bias,
    void* __restrict__ Cp,
    int M, int K, int ldc)
{
    __shared__ __align__(16) unsigned short smem[8192];   // As[128*32] | Ws[128*32]
    unsigned short* As = smem;
    unsigned short* Ws = smem + 4096;
    const int tid = threadIdx.x, lane = tid & 63, wave = tid >> 6;
    const int wr = (wave >> 1) << 6, wc = (wave & 1) << 6;
    const int m0 = blockIdx.x * 128, n0 = blockIdx.y * 128;
    const int l15 = lane & 15, l4 = lane >> 4;

    // W staging chunks (16B each): c = j*256 + wave*64 + lane, j=0,1
    const int cw = wave * 64 + lane;
    const unsigned short* gW0 = Wt + (size_t)(n0 + (cw >> 2)) * K + (cw & 3) * 8;
    const unsigned short* gW1 = Wt + (size_t)(n0 + ((cw + 256) >> 2)) * K + ((cw + 256) & 3) * 8;
    unsigned short* lW0 = Ws + cw * 8;
    unsigned short* lW1 = Ws + (cw + 256) * 8;

    // A staging
    const unsigned short* gA0; const unsigned short* gA1;
    unsigned short* lA0; unsigned short* lA1;
    const float* fA0; const float* fA1;
    unsigned short* sA0; unsigned short* sA1;
    if constexpr (AMODE == 0) {
        gA0 = (const unsigned short*)Ap + (size_t)(m0 + (cw >> 2)) * K + (cw & 3) * 8;
        gA1 = (const unsigned short*)Ap + (size_t)(m0 + ((cw + 256) >> 2)) * K + ((cw + 256) & 3) * 8;
        lA0 = As + cw * 8;
        lA1 = As + (cw + 256) * 8;
    } else {
        int c0 = tid, c1 = tid + 256;
        int r0 = m0 + (c0 >> 2); if (r0 >= M) r0 = M - 1;
        int r1 = m0 + (c1 >> 2); if (r1 >= M) r1 = M - 1;
        fA0 = (const float*)Ap + (size_t)r0 * K + (c0 & 3) * 8;
        fA1 = (const float*)Ap + (size_t)r1 * K + (c1 & 3) * 8;
        sA0 = As + c0 * 8;
        sA1 = As + c1 * 8;
    }

    f32x4 acc[4][4];
#pragma unroll
    for (int m = 0; m < 4; ++m)
#pragma unroll
        for (int n = 0; n < 4; ++n)
#pragma unroll
            for (int i = 0; i < 4; ++i) acc[m][n][i] = 0.f;

    const int nk = K >> 5;
    for (int kt = 0; kt < nk; ++kt) {
        if constexpr (AMODE == 0) {
            gload16(gA0, lA0);
            gload16(gA1, lA1);
            gA0 += 32; gA1 += 32;
        } else {
            *reinterpret_cast<us8*>(sA0) = cvt8(fA0);
            *reinterpret_cast<us8*>(sA1) = cvt8(fA1);
            fA0 += 32; fA1 += 32;
        }
        gload16(gW0, lW0);
        gload16(gW1, lW1);
        gW0 += 32; gW1 += 32;
        __syncthreads();
        bf16x8 a[4], b[4];
#pragma unroll
        for (int m = 0; m < 4; ++m)
            a[m] = lv8(&As[(wr + m * 16 + l15) * 32 + l4 * 8]);
#pragma unroll
        for (int n = 0; n < 4; ++n)
            b[n] = lv8(&Ws[(wc + n * 16 + l15) * 32 + l4 * 8]);
#pragma unroll
        for (int m = 0; m < 4; ++m)
#pragma unroll
            for (int n = 0; n < 4; ++n)
                acc[m][n] = __builtin_amdgcn_mfma_f32_16x16x32_bf16(a[m], b[n], acc[m][n], 0, 0, 0);
        __syncthreads();
    }

    float bs[4];
#pragma unroll
    for (int n = 0; n < 4; ++n) bs[n] = bias[n0 + wc + n * 16 + l15];

    if constexpr (CF32) {
        float* C = (float*)Cp;
#pragma unroll
        for (int n = 0; n < 4; ++n)
#pragma unroll
            for (int m = 0; m < 4; ++m)
#pragma unroll
                for (int i = 0; i < 4; ++i) {
                    const int r = m0 + wr + m * 16 + l4 * 4 + i;
                    if (r < M) C[(size_t)r * ldc + n0 + wc + n * 16 + l15] = acc[m][n][i] + bs[n];
                }
    } else {
        unsigned short* C = (unsigned short*)Cp;
#pragma unroll
        for (int p = 0; p < 2; ++p) {
            __syncthreads();
            if (wr == p * 64) {
#pragma unroll
                for (int m = 0; m < 4; ++m)
#pragma unroll
                    for (int n = 0; n < 4; ++n)
#pragma unroll
                        for (int i = 0; i < 4; ++i)
                            smem[(m * 16 + l4 * 4 + i) * 128 + wc + n * 16 + l15] =
                                f2b(acc[m][n][i] + bs[n]);
            }
            __syncthreads();
#pragma unroll
            for (int r = 0; r < 4; ++r) {
                const int off = (r * 256 + tid) * 8;
                const int row = off >> 7, col = off & 127;
                const int grow = m0 + p * 64 + row;
                if (grow < M)
                    *reinterpret_cast<us8*>(&C[(size_t)grow * ldc + n0 + col]) =
                        *reinterpret_cast<us8*>(&smem[off]);
            }
        }
    }
}

// ---------------- attention: per (128 q-rows, head, batch), all bf16 ws ----------------
__global__ __launch_bounds__(128) void attn_kernel(
    const unsigned short* __restrict__ Q,
    const unsigned short* __restrict__ Kp,
    const unsigned short* __restrict__ Vp,
    unsigned short* __restrict__ Oa)
{
    __shared__ __align__(16) unsigned short Kl[80 * 104];   // [kv][d] d padded to 96
    __shared__ __align__(16) unsigned short Vt[80 * 104];   // [d][kv] kv padded to 96
    __shared__ __align__(16) unsigned short Pl[2][64 * 104];// per-wave [q][kv]
    const int tid = threadIdx.x, lane = tid & 63, wave = tid >> 6;
    const int l15 = lane & 15, l4 = lane >> 4;
    const int qb = blockIdx.x * 128, h = blockIdx.y, b = blockIdx.z;
    const size_t kvbase = (size_t)b * SKV_ * E_ + (size_t)h * DH_;

    for (int idx = tid; idx < 160; idx += 128) {            // K cols 80..95
        int row = idx >> 1, seg = idx & 1;
        *reinterpret_cast<us8*>(&Kl[row * 104 + 80 + seg * 8]) = (us8){0,0,0,0,0,0,0,0};
    }
    for (int idx = tid; idx < 30; idx += 128) {             // K rows 77..79 cols 0..79
        int row = 77 + idx / 10, seg = idx % 10;
        *reinterpret_cast<us8*>(&Kl[row * 104 + seg * 8]) = (us8){0,0,0,0,0,0,0,0};
    }
    for (int idx = tid; idx < 80 * 19; idx += 128) {        // Vt cols 77..95
        int row = idx / 19, c = 77 + idx % 19;
        Vt[row * 104 + c] = 0;
    }
    for (int idx = tid; idx < 256; idx += 128) {            // P cols 80..95, both waves
        int w = idx >> 7, rem = idx & 127;
        int row = rem >> 1, seg = rem & 1;
        *reinterpret_cast<us8*>(&Pl[w][row * 104 + 80 + seg * 8]) = (us8){0,0,0,0,0,0,0,0};
    }
    for (int idx = tid; idx < 770; idx += 128) {            // stage K rows (vectorized)
        int kv = idx / 10, seg = idx % 10;
        *reinterpret_cast<us8*>(&Kl[kv * 104 + seg * 8]) =
            *reinterpret_cast<const us8*>(&Kp[kvbase + (size_t)kv * E_ + seg * 8]);
    }
    for (int idx = tid; idx < 770; idx += 128) {            // stage V transposed (vector loads)
        int kv = idx / 10, seg = idx % 10;
        us8 v = *reinterpret_cast<const us8*>(&Vp[kvbase + (size_t)kv * E_ + seg * 8]);
#pragma unroll
        for (int j = 0; j < 8; ++j)
            Vt[(seg * 8 + j) * 104 + kv] = v[j];
    }
    __syncthreads();

    f32x4 accS[4][5];
#pragma unroll
    for (int m = 0; m < 4; ++m)
#pragma unroll
        for (int n = 0; n < 5; ++n)
#pragma unroll
            for (int i = 0; i < 4; ++i) accS[m][n][i] = 0.f;

    const size_t qrow0 = (size_t)b * SQ_ + qb + wave * 64;
#pragma unroll
    for (int ks = 0; ks < 3; ++ks) {
        bf16x8 aq[4];
        const int d = ks * 32 + l4 * 8;
#pragma unroll
        for (int m = 0; m < 4; ++m) {
            if (d < 80)
                aq[m] = lv8(&Q[(qrow0 + m * 16 + l15) * E_ + h * DH_ + d]);
            else
                aq[m] = zero8();
        }
#pragma unroll
        for (int n = 0; n < 5; ++n) {
            bf16x8 bk = lv8(&Kl[(n * 16 + l15) * 104 + ks * 32 + l4 * 8]);
#pragma unroll
            for (int m = 0; m < 4; ++m)
                accS[m][n] = __builtin_amdgcn_mfma_f32_16x16x32_bf16(aq[m], bk, accS[m][n], 0, 0, 0);
        }
    }

    const float scale = 0.11180339887498949f; // 1/sqrt(80)
    float rs[4][4];
#pragma unroll
    for (int m = 0; m < 4; ++m) {
#pragma unroll
        for (int i = 0; i < 4; ++i) {
            float mx = -1e30f;
#pragma unroll
            for (int n = 0; n < 5; ++n) {
                float s = accS[m][n][i] * scale;
                if (n == 4 && l15 >= 13) s = -1e30f;   // kv = 64+l15 >= 77
                accS[m][n][i] = s;
                mx = fmaxf(mx, s);
            }
            mx = fmaxf(mx, __shfl_xor(mx, 1));
            mx = fmaxf(mx, __shfl_xor(mx, 2));
            mx = fmaxf(mx, __shfl_xor(mx, 4));
            mx = fmaxf(mx, __shfl_xor(mx, 8));
            float sum = 0.f;
            const int prow = m * 16 + l4 * 4 + i;
#pragma unroll
            for (int n = 0; n < 5; ++n) {
                float p = __expf(accS[m][n][i] - mx);
                sum += p;
                Pl[wave][prow * 104 + n * 16 + l15] = f2b(p);
            }
            sum += __shfl_xor(sum, 1);
            sum += __shfl_xor(sum, 2);
            sum += __shfl_xor(sum, 4);
            sum += __shfl_xor(sum, 8);
            rs[m][i] = sum;
        }
    }
    __syncthreads();

    f32x4 accO[4][5];
#pragma unroll
    for (int m = 0; m < 4; ++m)
#pragma unroll
        for (int n = 0; n < 5; ++n)
#pragma unroll
            for (int i = 0; i < 4; ++i) accO[m][n][i] = 0.f;
#pragma unroll
    for (int ks = 0; ks < 3; ++ks) {
        bf16x8 ap[4];
#pragma unroll
        for (int m = 0; m < 4; ++m)
            ap[m] = lv8(&Pl[wave][(m * 16 + l15) * 104 + ks * 32 + l4 * 8]);
#pragma unroll
        for (int n = 0; n < 5; ++n) {
            bf16x8 bv = lv8(&Vt[(n * 16 + l15) * 104 + ks * 32 + l4 * 8]);
#pragma unroll
            for (int m = 0; m < 4; ++m)
                accO[m][n] = __builtin_amdgcn_mfma_f32_16x16x32_bf16(ap[m], bv, accO[m][n], 0, 0, 0);
        }
    }
#pragma unroll
    for (int m = 0; m < 4; ++m) {
#pragma unroll
        for (int i = 0; i < 4; ++i) {
            const float inv = 1.f / rs[m][i];
            const size_t row = qrow0 + m * 16 + l4 * 4 + i;
#pragma unroll
            for (int n = 0; n < 5; ++n)
                Oa[row * E_ + h * DH_ + n * 16 + l15] = f2b(accO[m][n][i] * inv);
        }
    }
}

extern "C" void kernel_launch(void* const* d_in, const int* in_sizes, int n_in,
                              void* d_out, int out_size, void* d_ws, size_t ws_size,
                              hipStream_t stream) {
    const float* x  = (const float*)d_in[0];
    const float* y  = (const float*)d_in[1];
    const float* Wq = (const float*)d_in[2];
    const float* bq = (const float*)d_in[3];
    const float* Wk = (const float*)d_in[4];
    const float* bk = (const float*)d_in[5];
    const float* Wv = (const float*)d_in[6];
    const float* bv = (const float*)d_in[7];
    const float* Wo = (const float*)d_in[8];
    const float* bo = (const float*)d_in[9];
    float* out = (float*)d_out;

    char* ws = (char*)d_ws;
    unsigned short* WqT = (unsigned short*)(ws + 0);         //  819,200 B
    unsigned short* WkT = (unsigned short*)(ws + 819200);    //  983,040 B
    unsigned short* WvT = (unsigned short*)(ws + 1802240);   //  983,040 B
    unsigned short* WoT = (unsigned short*)(ws + 2785280);   //  819,200 B
    unsigned short* Qb  = (unsigned short*)(ws + 3604480);   // 41,943,040 B
    unsigned short* Kb  = (unsigned short*)(ws + 45547520);  //  3,153,920 B
    unsigned short* Vb  = (unsigned short*)(ws + 48701440);  //  3,153,920 B
    unsigned short* Xb  = (unsigned short*)(ws + 51855360);  // 41,943,040 B (big path only)
    const bool big = ws_size >= (size_t)(51855360 + 41943040);

    transpose_kernel<<<dim3(20, 20), 256, 0, stream>>>(Wq, WqT, 640, 640);
    transpose_kernel<<<dim3(20, 24), 256, 0, stream>>>(Wk, WkT, 768, 640);
    transpose_kernel<<<dim3(20, 24), 256, 0, stream>>>(Wv, WvT, 768, 640);
    transpose_kernel<<<dim3(20, 20), 256, 0, stream>>>(Wo, WoT, 640, 640);

    if (big) {
        convert_kernel<<<2048, 256, 0, stream>>>(x, Xb, (long)32768 * 640 / 8);
        gemm2<0, false><<<dim3(256, 5), 256, 0, stream>>>(Xb, WqT, bq, Qb, 32768, 640, 640);
    } else {
        gemm2<1, false><<<dim3(256, 5), 256, 0, stream>>>(x, WqT, bq, Qb, 32768, 640, 640);
    }
    gemm2<1, false><<<dim3(20, 5), 256, 0, stream>>>(y, WkT, bk, Kb, 2464, 768, 640);
    gemm2<1, false><<<dim3(20, 5), 256, 0, stream>>>(y, WvT, bv, Vb, 2464, 768, 640);

    attn_kernel<<<dim3(8, 8, 32), 128, 0, stream>>>(Qb, Kb, Vb, Qb);

    gemm2<0, true><<<dim3(256, 5), 256, 0, stream>>>(Qb, WoT, bo, out, 32768, 640, 640);
}

// Round 4
// 217.403 us; speedup vs baseline: 1.2755x; 1.1331x over previous
//
#include <hip/hip_runtime.h>
#include <hip/hip_bf16.h>

typedef __bf16 bf16x8 __attribute__((ext_vector_type(8)));
typedef float f32x4 __attribute__((ext_vector_type(4)));
typedef unsigned short us8 __attribute__((ext_vector_type(8)));

#define E_ 640
#define CD_ 768
#define B_ 32
#define SQ_ 1024
#define SKV_ 77
#define H_ 8
#define DH_ 80

typedef __attribute__((address_space(3))) unsigned int as3_u32;
typedef __attribute__((address_space(1))) const unsigned int as1_u32;

__device__ __forceinline__ void gload16(const unsigned short* g, unsigned short* l) {
    __builtin_amdgcn_global_load_lds((as1_u32*)g, (as3_u32*)l, 16, 0, 0);
}

__device__ __forceinline__ float b2f(unsigned short u) {
    unsigned int x = ((unsigned int)u) << 16;
    return __builtin_bit_cast(float, x);
}
__device__ __forceinline__ unsigned short f2b(float f) {
    unsigned int x = __builtin_bit_cast(unsigned int, f);
    x += 0x7fffu + ((x >> 16) & 1u);   // RNE
    return (unsigned short)(x >> 16);
}
__device__ __forceinline__ bf16x8 lv8(const unsigned short* p) {
    return __builtin_bit_cast(bf16x8, *reinterpret_cast<const us8*>(p));
}
__device__ __forceinline__ bf16x8 zero8() {
    us8 z = {0,0,0,0,0,0,0,0};
    return __builtin_bit_cast(bf16x8, z);
}
__device__ __forceinline__ us8 cvt8(const float* s) {
    f32x4 f0 = *reinterpret_cast<const f32x4*>(s);
    f32x4 f1 = *reinterpret_cast<const f32x4*>(s + 4);
    us8 v;
    v[0]=f2b(f0[0]); v[1]=f2b(f0[1]); v[2]=f2b(f0[2]); v[3]=f2b(f0[3]);
    v[4]=f2b(f1[0]); v[5]=f2b(f1[1]); v[6]=f2b(f1[2]); v[7]=f2b(f1[3]);
    return v;
}

// ---------------- convert: fp32 -> bf16 ----------------
__global__ __launch_bounds__(256) void convert_kernel(
    const float* __restrict__ in, unsigned short* __restrict__ out, long n8)
{
    long i = (long)blockIdx.x * 256 + threadIdx.x;
    const long stride = (long)gridDim.x * 256;
    for (; i < n8; i += stride)
        *reinterpret_cast<us8*>(out + i * 8) = cvt8(in + i * 8);
}

// ---------------- transpose+cast pair: two f32 [K][N] -> bf16 [N][K] ----------------
__global__ __launch_bounds__(256) void transpose2_kernel(
    const float* __restrict__ inA, unsigned short* __restrict__ outA,
    const float* __restrict__ inB, unsigned short* __restrict__ outB,
    int K, int N)
{
    const float* in = blockIdx.z ? inB : inA;
    unsigned short* out = blockIdx.z ? outB : outA;
    __shared__ unsigned short t[32][33];
    const int tx = threadIdx.x & 31, ty = threadIdx.x >> 5;
    const int n0 = blockIdx.x * 32, k0 = blockIdx.y * 32;
#pragma unroll
    for (int i = 0; i < 4; ++i)
        t[ty + 8*i][tx] = f2b(in[(size_t)(k0 + ty + 8*i) * N + n0 + tx]);
    __syncthreads();
#pragma unroll
    for (int i = 0; i < 4; ++i)
        out[(size_t)(n0 + ty + 8*i) * K + k0 + tx] = t[tx][ty + 8*i];
}

// ---------------- GEMM body: C[M][ldc] = A[M][K] @ Wt^T + bias ----------------
template<int AMODE, bool CF32>
__device__ __forceinline__ void gemm_body(
    const void* __restrict__ Ap,
    const unsigned short* __restrict__ Wt,
    const float* __restrict__ bias,
    void* __restrict__ Cp,
    int M, int K, int ldc)
{
    __shared__ __align__(16) unsigned short smem[8192];   // As[128*32] | Ws[128*32]
    unsigned short* As = smem;
    unsigned short* Ws = smem + 4096;
    const int tid = threadIdx.x, lane = tid & 63, wave = tid >> 6;
    const int wr = (wave >> 1) << 6, wc = (wave & 1) << 6;
    const int m0 = blockIdx.x * 128, n0 = blockIdx.y * 128;
    const int l15 = lane & 15, l4 = lane >> 4;

    const int cw = wave * 64 + lane;
    const unsigned short* gW0 = Wt + (size_t)(n0 + (cw >> 2)) * K + (cw & 3) * 8;
    const unsigned short* gW1 = Wt + (size_t)(n0 + ((cw + 256) >> 2)) * K + ((cw + 256) & 3) * 8;
    unsigned short* lW0 = Ws + cw * 8;
    unsigned short* lW1 = Ws + (cw + 256) * 8;

    const unsigned short* gA0; const unsigned short* gA1;
    unsigned short* lA0; unsigned short* lA1;
    const float* fA0; const float* fA1;
    unsigned short* sA0; unsigned short* sA1;
    if constexpr (AMODE == 0) {
        gA0 = (const unsigned short*)Ap + (size_t)(m0 + (cw >> 2)) * K + (cw & 3) * 8;
        gA1 = (const unsigned short*)Ap + (size_t)(m0 + ((cw + 256) >> 2)) * K + ((cw + 256) & 3) * 8;
        lA0 = As + cw * 8;
        lA1 = As + (cw + 256) * 8;
    } else {
        int c0 = tid, c1 = tid + 256;
        int r0 = m0 + (c0 >> 2); if (r0 >= M) r0 = M - 1;
        int r1 = m0 + (c1 >> 2); if (r1 >= M) r1 = M - 1;
        fA0 = (const float*)Ap + (size_t)r0 * K + (c0 & 3) * 8;
        fA1 = (const float*)Ap + (size_t)r1 * K + (c1 & 3) * 8;
        sA0 = As + c0 * 8;
        sA1 = As + c1 * 8;
    }

    f32x4 acc[4][4];
#pragma unroll
    for (int m = 0; m < 4; ++m)
#pragma unroll
        for (int n = 0; n < 4; ++n)
#pragma unroll
            for (int i = 0; i < 4; ++i) acc[m][n][i] = 0.f;

    const int nk = K >> 5;
    for (int kt = 0; kt < nk; ++kt) {
        if constexpr (AMODE == 0) {
            gload16(gA0, lA0);
            gload16(gA1, lA1);
            gA0 += 32; gA1 += 32;
        } else {
            *reinterpret_cast<us8*>(sA0) = cvt8(fA0);
            *reinterpret_cast<us8*>(sA1) = cvt8(fA1);
            fA0 += 32; fA1 += 32;
        }
        gload16(gW0, lW0);
        gload16(gW1, lW1);
        gW0 += 32; gW1 += 32;
        __syncthreads();
        bf16x8 a[4], b[4];
#pragma unroll
        for (int m = 0; m < 4; ++m)
            a[m] = lv8(&As[(wr + m * 16 + l15) * 32 + l4 * 8]);
#pragma unroll
        for (int n = 0; n < 4; ++n)
            b[n] = lv8(&Ws[(wc + n * 16 + l15) * 32 + l4 * 8]);
#pragma unroll
        for (int m = 0; m < 4; ++m)
#pragma unroll
            for (int n = 0; n < 4; ++n)
                acc[m][n] = __builtin_amdgcn_mfma_f32_16x16x32_bf16(a[m], b[n], acc[m][n], 0, 0, 0);
        __syncthreads();
    }

    float bs[4];
#pragma unroll
    for (int n = 0; n < 4; ++n) bs[n] = bias[n0 + wc + n * 16 + l15];

    if constexpr (CF32) {
        float* C = (float*)Cp;
#pragma unroll
        for (int n = 0; n < 4; ++n)
#pragma unroll
            for (int m = 0; m < 4; ++m)
#pragma unroll
                for (int i = 0; i < 4; ++i) {
                    const int r = m0 + wr + m * 16 + l4 * 4 + i;
                    if (r < M) C[(size_t)r * ldc + n0 + wc + n * 16 + l15] = acc[m][n][i] + bs[n];
                }
    } else {
        unsigned short* C = (unsigned short*)Cp;
#pragma unroll
        for (int p = 0; p < 2; ++p) {
            __syncthreads();
            if (wr == p * 64) {
#pragma unroll
                for (int m = 0; m < 4; ++m)
#pragma unroll
                    for (int n = 0; n < 4; ++n)
#pragma unroll
                        for (int i = 0; i < 4; ++i)
                            smem[(m * 16 + l4 * 4 + i) * 128 + wc + n * 16 + l15] =
                                f2b(acc[m][n][i] + bs[n]);
            }
            __syncthreads();
#pragma unroll
            for (int r = 0; r < 4; ++r) {
                const int off = (r * 256 + tid) * 8;
                const int row = off >> 7, col = off & 127;
                const int grow = m0 + p * 64 + row;
                if (grow < M)
                    *reinterpret_cast<us8*>(&C[(size_t)grow * ldc + n0 + col]) =
                        *reinterpret_cast<us8*>(&smem[off]);
            }
        }
    }
}

template<int AMODE, bool CF32>
__global__ __launch_bounds__(256) void gemm2(
    const void* __restrict__ Ap, const unsigned short* __restrict__ Wt,
    const float* __restrict__ bias, void* __restrict__ Cp, int M, int K, int ldc)
{
    gemm_body<AMODE, CF32>(Ap, Wt, bias, Cp, M, K, ldc);
}

// fused K-proj + V-proj (blockIdx.z selects)
__global__ __launch_bounds__(256) void gemm_kv(
    const float* __restrict__ y,
    const unsigned short* __restrict__ WkT, const float* __restrict__ bk2, unsigned short* __restrict__ Kb,
    const unsigned short* __restrict__ WvT, const float* __restrict__ bv2, unsigned short* __restrict__ Vb)
{
    const unsigned short* Wt = blockIdx.z ? WvT : WkT;
    const float* bias = blockIdx.z ? bv2 : bk2;
    unsigned short* C = blockIdx.z ? Vb : Kb;
    gemm_body<1, false>(y, Wt, bias, C, 2464, 768, 640);
}

// ---------------- attention: per (128 q-rows, head, batch) ----------------
// LDS layout: smem[0..11264)  = Kl [80][88]  -> later P [2][64][88] -> later O [128][80]
//             smem[11264..18304) = Vt [80][88]
__global__ __launch_bounds__(128) void attn_kernel(
    const unsigned short* __restrict__ Q,
    const unsigned short* __restrict__ Kp,
    const unsigned short* __restrict__ Vp,
    unsigned short* __restrict__ Oa)
{
    __shared__ __align__(16) unsigned short smem[18320];  // +16 guard (speculative b128 reads)
    unsigned short* Kl = smem;            // [80][88]
    unsigned short* Vt = smem + 11264;    // [80][88]
    const int tid = threadIdx.x, lane = tid & 63, wave = tid >> 6;
    const int l15 = lane & 15, l4 = lane >> 4;
    const int qb = blockIdx.x * 128, h = blockIdx.y, b = blockIdx.z;
    const size_t kvbase = (size_t)b * SKV_ * E_ + (size_t)h * DH_;
    const size_t qrow0 = (size_t)b * SQ_ + qb + wave * 64;

    // --- hoisted Q fragment loads (overlap with K/V staging) ---
    bf16x8 aq[3][4];
#pragma unroll
    for (int ks = 0; ks < 3; ++ks) {
        const int d = ks * 32 + l4 * 8;
#pragma unroll
        for (int m = 0; m < 4; ++m)
            aq[ks][m] = (d < 80) ? lv8(&Q[(qrow0 + m * 16 + l15) * E_ + h * DH_ + d]) : zero8();
    }

    // --- stage K [77][80] + zero rows 77..79 ---
    for (int idx = tid; idx < 770; idx += 128) {
        int kv = idx / 10, seg = idx % 10;
        *reinterpret_cast<us8*>(&Kl[kv * 88 + seg * 8]) =
            *reinterpret_cast<const us8*>(&Kp[kvbase + (size_t)kv * E_ + seg * 8]);
    }
    for (int idx = tid; idx < 30; idx += 128) {
        int row = 77 + idx / 10, seg = idx % 10;
        *reinterpret_cast<us8*>(&Kl[row * 88 + seg * 8]) = (us8){0,0,0,0,0,0,0,0};
    }
    // --- zero Vt cols 77..87, stage V transposed ---
    for (int idx = tid; idx < 880; idx += 128) {
        int d = idx / 11, c = 77 + idx % 11;
        Vt[d * 88 + c] = 0;
    }
    for (int idx = tid; idx < 770; idx += 128) {
        int kv = idx / 10, seg = idx % 10;
        us8 v = *reinterpret_cast<const us8*>(&Vp[kvbase + (size_t)kv * E_ + seg * 8]);
#pragma unroll
        for (int j = 0; j < 8; ++j)
            Vt[(seg * 8 + j) * 88 + kv] = v[j];
    }
    __syncthreads();

    // --- scores = Q K^T ---
    f32x4 accS[4][5];
#pragma unroll
    for (int m = 0; m < 4; ++m)
#pragma unroll
        for (int n = 0; n < 5; ++n)
#pragma unroll
            for (int i = 0; i < 4; ++i) accS[m][n][i] = 0.f;

    __builtin_amdgcn_s_setprio(1);
#pragma unroll
    for (int ks = 0; ks < 3; ++ks) {
#pragma unroll
        for (int n = 0; n < 5; ++n) {
            bf16x8 bk = (ks < 2 || l4 < 2) ? lv8(&Kl[(n * 16 + l15) * 88 + ks * 32 + l4 * 8])
                                           : zero8();
#pragma unroll
            for (int m = 0; m < 4; ++m)
                accS[m][n] = __builtin_amdgcn_mfma_f32_16x16x32_bf16(aq[ks][m], bk, accS[m][n], 0, 0, 0);
        }
    }
    __builtin_amdgcn_s_setprio(0);
    __syncthreads();   // all waves done reading Kl; region becomes P

    unsigned short* Pw = smem + wave * 5632;   // [64][88]

    // --- softmax ---
    const float scale = 0.11180339887498949f; // 1/sqrt(80)
    float rs[4][4];
#pragma unroll
    for (int m = 0; m < 4; ++m) {
#pragma unroll
        for (int i = 0; i < 4; ++i) {
            float mx = -1e30f;
#pragma unroll
            for (int n = 0; n < 5; ++n) {
                float s = accS[m][n][i] * scale;
                if (n == 4 && l15 >= 13) s = -1e30f;   // kv = 64+l15 >= 77
                accS[m][n][i] = s;
                mx = fmaxf(mx, s);
            }
            mx = fmaxf(mx, __shfl_xor(mx, 1));
            mx = fmaxf(mx, __shfl_xor(mx, 2));
            mx = fmaxf(mx, __shfl_xor(mx, 4));
            mx = fmaxf(mx, __shfl_xor(mx, 8));
            float sum = 0.f;
            const int prow = m * 16 + l4 * 4 + i;
#pragma unroll
            for (int n = 0; n < 5; ++n) {
                float p = __expf(accS[m][n][i] - mx);
                sum += p;
                Pw[prow * 88 + n * 16 + l15] = f2b(p);
            }
            sum += __shfl_xor(sum, 1);
            sum += __shfl_xor(sum, 2);
            sum += __shfl_xor(sum, 4);
            sum += __shfl_xor(sum, 8);
            rs[m][i] = sum;
        }
    }

    // --- out = P V (same-wave P; no barrier needed) ---
    f32x4 accO[4][5];
#pragma unroll
    for (int m = 0; m < 4; ++m)
#pragma unroll
        for (int n = 0; n < 5; ++n)
#pragma unroll
            for (int i = 0; i < 4; ++i) accO[m][n][i] = 0.f;

    __builtin_amdgcn_s_setprio(1);
#pragma unroll
    for (int ks = 0; ks < 3; ++ks) {
        bf16x8 ap[4];
#pragma unroll
        for (int m = 0; m < 4; ++m)
            ap[m] = (ks < 2 || l4 < 2) ? lv8(&Pw[(m * 16 + l15) * 88 + ks * 32 + l4 * 8])
                                       : zero8();
#pragma unroll
        for (int n = 0; n < 5; ++n) {
            bf16x8 bv = (ks < 2 || l4 < 2) ? lv8(&Vt[(n * 16 + l15) * 88 + ks * 32 + l4 * 8])
                                           : zero8();
#pragma unroll
            for (int m = 0; m < 4; ++m)
                accO[m][n] = __builtin_amdgcn_mfma_f32_16x16x32_bf16(ap[m], bv, accO[m][n], 0, 0, 0);
        }
    }
    __builtin_amdgcn_s_setprio(0);

    // --- stage O in LDS, coalesced write-out ---
    __syncthreads();   // everyone done with P/Vt reads; region becomes O [128][80]
#pragma unroll
    for (int m = 0; m < 4; ++m) {
#pragma unroll
        for (int i = 0; i < 4; ++i) {
            const float inv = 1.f / rs[m][i];
            const int rl = wave * 64 + m * 16 + l4 * 4 + i;
#pragma unroll
            for (int n = 0; n < 5; ++n)
                smem[rl * 80 + n * 16 + l15] = f2b(accO[m][n][i] * inv);
        }
    }
    __syncthreads();
    const size_t obase = (size_t)b * SQ_ + qb;
    for (int idx = tid; idx < 1280; idx += 128) {
        int row = idx / 10, seg = idx % 10;
        *reinterpret_cast<us8*>(&Oa[(obase + row) * E_ + h * DH_ + seg * 8]) =
            *reinterpret_cast<us8*>(&smem[row * 80 + seg * 8]);
    }
}

extern "C" void kernel_launch(void* const* d_in, const int* in_sizes, int n_in,
                              void* d_out, int out_size, void* d_ws, size_t ws_size,
                              hipStream_t stream) {
    const float* x  = (const float*)d_in[0];
    const float* y  = (const float*)d_in[1];
    const float* Wq = (const float*)d_in[2];
    const float* bq = (const float*)d_in[3];
    const float* Wk = (const float*)d_in[4];
    const float* bk = (const float*)d_in[5];
    const float* Wv = (const float*)d_in[6];
    const float* bv = (const float*)d_in[7];
    const float* Wo = (const float*)d_in[8];
    const float* bo = (const float*)d_in[9];
    float* out = (float*)d_out;

    char* ws = (char*)d_ws;
    unsigned short* WqT = (unsigned short*)(ws + 0);         //  819,200 B
    unsigned short* WkT = (unsigned short*)(ws + 819200);    //  983,040 B
    unsigned short* WvT = (unsigned short*)(ws + 1802240);   //  983,040 B
    unsigned short* WoT = (unsigned short*)(ws + 2785280);   //  819,200 B
    unsigned short* Qb  = (unsigned short*)(ws + 3604480);   // 41,943,040 B
    unsigned short* Kb  = (unsigned short*)(ws + 45547520);  //  3,153,920 B
    unsigned short* Vb  = (unsigned short*)(ws + 48701440);  //  3,153,920 B
    unsigned short* Xb  = (unsigned short*)(ws + 51855360);  // 41,943,040 B (big path only)
    const bool big = ws_size >= (size_t)(51855360 + 41943040);

    transpose2_kernel<<<dim3(20, 20, 2), 256, 0, stream>>>(Wq, WqT, Wo, WoT, 640, 640);
    transpose2_kernel<<<dim3(20, 24, 2), 256, 0, stream>>>(Wk, WkT, Wv, WvT, 768, 640);

    if (big) {
        convert_kernel<<<2048, 256, 0, stream>>>(x, Xb, (long)32768 * 640 / 8);
        gemm2<0, false><<<dim3(256, 5), 256, 0, stream>>>(Xb, WqT, bq, Qb, 32768, 640, 640);
    } else {
        gemm2<1, false><<<dim3(256, 5), 256, 0, stream>>>(x, WqT, bq, Qb, 32768, 640, 640);
    }
    gemm_kv<<<dim3(20, 5, 2), 256, 0, stream>>>(y, WkT, bk, Kb, WvT, bv, Vb);

    attn_kernel<<<dim3(8, 8, 32), 128, 0, stream>>>(Qb, Kb, Vb, Qb);

    gemm2<0, true><<<dim3(256, 5), 256, 0, stream>>>(Qb, WoT, bo, out, 32768, 640, 640);
}

// Round 5
// 215.846 us; speedup vs baseline: 1.2847x; 1.0072x over previous
//
#include <hip/hip_runtime.h>
#include <hip/hip_bf16.h>

typedef __bf16 bf16x8 __attribute__((ext_vector_type(8)));
typedef float f32x4 __attribute__((ext_vector_type(4)));
typedef unsigned short us8 __attribute__((ext_vector_type(8)));

#define E_ 640
#define CD_ 768
#define B_ 32
#define SQ_ 1024
#define SKV_ 77
#define H_ 8
#define DH_ 80

typedef __attribute__((address_space(3))) unsigned int as3_u32;
typedef __attribute__((address_space(1))) const unsigned int as1_u32;

__device__ __forceinline__ void gload16(const unsigned short* g, unsigned short* l) {
    __builtin_amdgcn_global_load_lds((as1_u32*)g, (as3_u32*)l, 16, 0, 0);
}

__device__ __forceinline__ float b2f(unsigned short u) {
    unsigned int x = ((unsigned int)u) << 16;
    return __builtin_bit_cast(float, x);
}
__device__ __forceinline__ unsigned short f2b(float f) {
    unsigned int x = __builtin_bit_cast(unsigned int, f);
    x += 0x7fffu + ((x >> 16) & 1u);   // RNE
    return (unsigned short)(x >> 16);
}
__device__ __forceinline__ bf16x8 lv8(const unsigned short* p) {
    return __builtin_bit_cast(bf16x8, *reinterpret_cast<const us8*>(p));
}
__device__ __forceinline__ bf16x8 zero8() {
    us8 z = {0,0,0,0,0,0,0,0};
    return __builtin_bit_cast(bf16x8, z);
}
__device__ __forceinline__ us8 cvt8(const float* s) {
    f32x4 f0 = *reinterpret_cast<const f32x4*>(s);
    f32x4 f1 = *reinterpret_cast<const f32x4*>(s + 4);
    us8 v;
    v[0]=f2b(f0[0]); v[1]=f2b(f0[1]); v[2]=f2b(f0[2]); v[3]=f2b(f0[3]);
    v[4]=f2b(f1[0]); v[5]=f2b(f1[1]); v[6]=f2b(f1[2]); v[7]=f2b(f1[3]);
    return v;
}

// ---------------- convert: fp32 -> bf16 ----------------
__global__ __launch_bounds__(256) void convert_kernel(
    const float* __restrict__ in, unsigned short* __restrict__ out, long n8)
{
    long i = (long)blockIdx.x * 256 + threadIdx.x;
    const long stride = (long)gridDim.x * 256;
    for (; i < n8; i += stride)
        *reinterpret_cast<us8*>(out + i * 8) = cvt8(in + i * 8);
}

// ---------------- transpose+cast pair: two f32 [K][N] -> bf16 [N][K] ----------------
__global__ __launch_bounds__(256) void transpose2_kernel(
    const float* __restrict__ inA, unsigned short* __restrict__ outA,
    const float* __restrict__ inB, unsigned short* __restrict__ outB,
    int K, int N)
{
    const float* in = blockIdx.z ? inB : inA;
    unsigned short* out = blockIdx.z ? outB : outA;
    __shared__ unsigned short t[32][33];
    const int tx = threadIdx.x & 31, ty = threadIdx.x >> 5;
    const int n0 = blockIdx.x * 32, k0 = blockIdx.y * 32;
#pragma unroll
    for (int i = 0; i < 4; ++i)
        t[ty + 8*i][tx] = f2b(in[(size_t)(k0 + ty + 8*i) * N + n0 + tx]);
    __syncthreads();
#pragma unroll
    for (int i = 0; i < 4; ++i)
        out[(size_t)(n0 + ty + 8*i) * K + k0 + tx] = t[tx][ty + 8*i];
}

// ---------------- GEMM body: C[M][ldc] = A[M][K] @ Wt^T + bias ----------------
// 2-phase double-buffered K-loop (T3 minimum recipe). 32 KB LDS.
template<int AMODE, bool CF32>
__device__ __forceinline__ void gemm_body(
    const void* __restrict__ Ap,
    const unsigned short* __restrict__ Wt,
    const float* __restrict__ bias,
    void* __restrict__ Cp,
    int M, int K, int ldc)
{
    __shared__ __align__(16) unsigned short smem[16384];   // 2 x {As[128*32] | Ws[128*32]}
    const int tid = threadIdx.x, lane = tid & 63, wave = tid >> 6;
    const int wr = (wave >> 1) << 6, wc = (wave & 1) << 6;
    const int m0 = blockIdx.x * 128, n0 = blockIdx.y * 128;
    const int l15 = lane & 15, l4 = lane >> 4;

    const int cw = wave * 64 + lane;
    const unsigned short* gW0 = Wt + (size_t)(n0 + (cw >> 2)) * K + (cw & 3) * 8;
    const unsigned short* gW1 = Wt + (size_t)(n0 + ((cw + 256) >> 2)) * K + ((cw + 256) & 3) * 8;

    const unsigned short* gA0; const unsigned short* gA1;
    const float* fA0; const float* fA1;
    if constexpr (AMODE == 0) {
        gA0 = (const unsigned short*)Ap + (size_t)(m0 + (cw >> 2)) * K + (cw & 3) * 8;
        gA1 = (const unsigned short*)Ap + (size_t)(m0 + ((cw + 256) >> 2)) * K + ((cw + 256) & 3) * 8;
    } else {
        int c0 = tid, c1 = tid + 256;
        int r0 = m0 + (c0 >> 2); if (r0 >= M) r0 = M - 1;
        int r1 = m0 + (c1 >> 2); if (r1 >= M) r1 = M - 1;
        fA0 = (const float*)Ap + (size_t)r0 * K + (c0 & 3) * 8;
        fA1 = (const float*)Ap + (size_t)r1 * K + (c1 & 3) * 8;
    }

    f32x4 acc[4][4];
#pragma unroll
    for (int m = 0; m < 4; ++m)
#pragma unroll
        for (int n = 0; n < 4; ++n)
#pragma unroll
            for (int i = 0; i < 4; ++i) acc[m][n][i] = 0.f;

    auto STAGE = [&](int buf) {
        unsigned short* As = smem + buf * 8192;
        unsigned short* Ws = As + 4096;
        if constexpr (AMODE == 0) {
            gload16(gA0, As + cw * 8);
            gload16(gA1, As + (cw + 256) * 8);
            gA0 += 32; gA1 += 32;
        } else {
            *reinterpret_cast<us8*>(As + tid * 8) = cvt8(fA0);
            *reinterpret_cast<us8*>(As + (tid + 256) * 8) = cvt8(fA1);
            fA0 += 32; fA1 += 32;
        }
        gload16(gW0, Ws + cw * 8);
        gload16(gW1, Ws + (cw + 256) * 8);
        gW0 += 32; gW1 += 32;
    };
    auto COMPUTE = [&](int buf) {
        const unsigned short* As = smem + buf * 8192;
        const unsigned short* Ws = As + 4096;
        bf16x8 a[4], b[4];
#pragma unroll
        for (int m = 0; m < 4; ++m)
            a[m] = lv8(&As[(wr + m * 16 + l15) * 32 + l4 * 8]);
#pragma unroll
        for (int n = 0; n < 4; ++n)
            b[n] = lv8(&Ws[(wc + n * 16 + l15) * 32 + l4 * 8]);
        __builtin_amdgcn_s_setprio(1);
#pragma unroll
        for (int m = 0; m < 4; ++m)
#pragma unroll
            for (int n = 0; n < 4; ++n)
                acc[m][n] = __builtin_amdgcn_mfma_f32_16x16x32_bf16(a[m], b[n], acc[m][n], 0, 0, 0);
        __builtin_amdgcn_s_setprio(0);
    };

    const int nk = K >> 5;   // 20 or 24, always even and >= 4
    STAGE(0);
    __syncthreads();
    for (int kt = 0; kt < nk - 2; kt += 2) {
        STAGE(1);
        COMPUTE(0);
        __syncthreads();
        STAGE(0);
        COMPUTE(1);
        __syncthreads();
    }
    STAGE(1);
    COMPUTE(0);
    __syncthreads();
    COMPUTE(1);

    float bs[4];
#pragma unroll
    for (int n = 0; n < 4; ++n) bs[n] = bias[n0 + wc + n * 16 + l15];

    if constexpr (CF32) {
        // coalesced fp32 epilogue: LDS-staged 64x128 float tile, 2 passes
        float* C = (float*)Cp;
        float* fs = (float*)smem;
#pragma unroll
        for (int p = 0; p < 2; ++p) {
            __syncthreads();
            if (wr == p * 64) {
#pragma unroll
                for (int m = 0; m < 4; ++m)
#pragma unroll
                    for (int n = 0; n < 4; ++n)
#pragma unroll
                        for (int i = 0; i < 4; ++i)
                            fs[(m * 16 + l4 * 4 + i) * 128 + wc + n * 16 + l15] =
                                acc[m][n][i] + bs[n];
            }
            __syncthreads();
#pragma unroll
            for (int r = 0; r < 8; ++r) {
                const int off = (r * 256 + tid) * 4;
                const int row = off >> 7, col = off & 127;
                const int grow = m0 + p * 64 + row;
                if (grow < M)
                    *reinterpret_cast<f32x4*>(&C[(size_t)grow * ldc + n0 + col]) =
                        *reinterpret_cast<const f32x4*>(&fs[off]);
            }
        }
    } else {
        unsigned short* C = (unsigned short*)Cp;
#pragma unroll
        for (int p = 0; p < 2; ++p) {
            __syncthreads();
            if (wr == p * 64) {
#pragma unroll
                for (int m = 0; m < 4; ++m)
#pragma unroll
                    for (int n = 0; n < 4; ++n)
#pragma unroll
                        for (int i = 0; i < 4; ++i)
                            smem[(m * 16 + l4 * 4 + i) * 128 + wc + n * 16 + l15] =
                                f2b(acc[m][n][i] + bs[n]);
            }
            __syncthreads();
#pragma unroll
            for (int r = 0; r < 4; ++r) {
                const int off = (r * 256 + tid) * 8;
                const int row = off >> 7, col = off & 127;
                const int grow = m0 + p * 64 + row;
                if (grow < M)
                    *reinterpret_cast<us8*>(&C[(size_t)grow * ldc + n0 + col]) =
                        *reinterpret_cast<us8*>(&smem[off]);
            }
        }
    }
}

template<int AMODE, bool CF32>
__global__ __launch_bounds__(256) void gemm2(
    const void* __restrict__ Ap, const unsigned short* __restrict__ Wt,
    const float* __restrict__ bias, void* __restrict__ Cp, int M, int K, int ldc)
{
    gemm_body<AMODE, CF32>(Ap, Wt, bias, Cp, M, K, ldc);
}

// fused K-proj + V-proj (blockIdx.z selects)
__global__ __launch_bounds__(256) void gemm_kv(
    const float* __restrict__ y,
    const unsigned short* __restrict__ WkT, const float* __restrict__ bk2, unsigned short* __restrict__ Kb,
    const unsigned short* __restrict__ WvT, const float* __restrict__ bv2, unsigned short* __restrict__ Vb)
{
    const unsigned short* Wt = blockIdx.z ? WvT : WkT;
    const float* bias = blockIdx.z ? bv2 : bk2;
    unsigned short* C = blockIdx.z ? Vb : Kb;
    gemm_body<1, false>(y, Wt, bias, C, 2464, 768, 640);
}

// ---------------- attention: per (128 q-rows, head, batch) ----------------
// LDS layout: smem[0..11264)  = Kl [80][88]  -> later P [2][64][88] -> later O [128][80]
//             smem[11264..18304) = Vt [80][88]
__global__ __launch_bounds__(128) void attn_kernel(
    const unsigned short* __restrict__ Q,
    const unsigned short* __restrict__ Kp,
    const unsigned short* __restrict__ Vp,
    unsigned short* __restrict__ Oa)
{
    __shared__ __align__(16) unsigned short smem[18320];  // +16 guard (speculative b128 reads)
    unsigned short* Kl = smem;            // [80][88]
    unsigned short* Vt = smem + 11264;    // [80][88]
    const int tid = threadIdx.x, lane = tid & 63, wave = tid >> 6;
    const int l15 = lane & 15, l4 = lane >> 4;
    const int qb = blockIdx.x * 128, h = blockIdx.y, b = blockIdx.z;
    const size_t kvbase = (size_t)b * SKV_ * E_ + (size_t)h * DH_;
    const size_t qrow0 = (size_t)b * SQ_ + qb + wave * 64;

    // --- hoisted Q fragment loads (overlap with K/V staging) ---
    bf16x8 aq[3][4];
#pragma unroll
    for (int ks = 0; ks < 3; ++ks) {
        const int d = ks * 32 + l4 * 8;
#pragma unroll
        for (int m = 0; m < 4; ++m)
            aq[ks][m] = (d < 80) ? lv8(&Q[(qrow0 + m * 16 + l15) * E_ + h * DH_ + d]) : zero8();
    }

    // --- stage K [77][80] + zero rows 77..79 ---
    for (int idx = tid; idx < 770; idx += 128) {
        int kv = idx / 10, seg = idx % 10;
        *reinterpret_cast<us8*>(&Kl[kv * 88 + seg * 8]) =
            *reinterpret_cast<const us8*>(&Kp[kvbase + (size_t)kv * E_ + seg * 8]);
    }
    for (int idx = tid; idx < 30; idx += 128) {
        int row = 77 + idx / 10, seg = idx % 10;
        *reinterpret_cast<us8*>(&Kl[row * 88 + seg * 8]) = (us8){0,0,0,0,0,0,0,0};
    }
    // --- zero Vt cols 77..87, stage V transposed ---
    for (int idx = tid; idx < 880; idx += 128) {
        int d = idx / 11, c = 77 + idx % 11;
        Vt[d * 88 + c] = 0;
    }
    for (int idx = tid; idx < 770; idx += 128) {
        int kv = idx / 10, seg = idx % 10;
        us8 v = *reinterpret_cast<const us8*>(&Vp[kvbase + (size_t)kv * E_ + seg * 8]);
#pragma unroll
        for (int j = 0; j < 8; ++j)
            Vt[(seg * 8 + j) * 88 + kv] = v[j];
    }
    __syncthreads();

    // --- scores = Q K^T ---
    f32x4 accS[4][5];
#pragma unroll
    for (int m = 0; m < 4; ++m)
#pragma unroll
        for (int n = 0; n < 5; ++n)
#pragma unroll
            for (int i = 0; i < 4; ++i) accS[m][n][i] = 0.f;

    __builtin_amdgcn_s_setprio(1);
#pragma unroll
    for (int ks = 0; ks < 3; ++ks) {
#pragma unroll
        for (int n = 0; n < 5; ++n) {
            bf16x8 bk = (ks < 2 || l4 < 2) ? lv8(&Kl[(n * 16 + l15) * 88 + ks * 32 + l4 * 8])
                                           : zero8();
#pragma unroll
            for (int m = 0; m < 4; ++m)
                accS[m][n] = __builtin_amdgcn_mfma_f32_16x16x32_bf16(aq[ks][m], bk, accS[m][n], 0, 0, 0);
        }
    }
    __builtin_amdgcn_s_setprio(0);
    __syncthreads();   // all waves done reading Kl; region becomes P

    unsigned short* Pw = smem + wave * 5632;   // [64][88]

    // --- softmax ---
    const float scale = 0.11180339887498949f; // 1/sqrt(80)
    float rs[4][4];
#pragma unroll
    for (int m = 0; m < 4; ++m) {
#pragma unroll
        for (int i = 0; i < 4; ++i) {
            float mx = -1e30f;
#pragma unroll
            for (int n = 0; n < 5; ++n) {
                float s = accS[m][n][i] * scale;
                if (n == 4 && l15 >= 13) s = -1e30f;   // kv = 64+l15 >= 77
                accS[m][n][i] = s;
                mx = fmaxf(mx, s);
            }
            mx = fmaxf(mx, __shfl_xor(mx, 1));
            mx = fmaxf(mx, __shfl_xor(mx, 2));
            mx = fmaxf(mx, __shfl_xor(mx, 4));
            mx = fmaxf(mx, __shfl_xor(mx, 8));
            float sum = 0.f;
            const int prow = m * 16 + l4 * 4 + i;
#pragma unroll
            for (int n = 0; n < 5; ++n) {
                float p = __expf(accS[m][n][i] - mx);
                sum += p;
                Pw[prow * 88 + n * 16 + l15] = f2b(p);
            }
            sum += __shfl_xor(sum, 1);
            sum += __shfl_xor(sum, 2);
            sum += __shfl_xor(sum, 4);
            sum += __shfl_xor(sum, 8);
            rs[m][i] = sum;
        }
    }

    // --- out = P V (same-wave P; no barrier needed) ---
    f32x4 accO[4][5];
#pragma unroll
    for (int m = 0; m < 4; ++m)
#pragma unroll
        for (int n = 0; n < 5; ++n)
#pragma unroll
            for (int i = 0; i < 4; ++i) accO[m][n][i] = 0.f;

    __builtin_amdgcn_s_setprio(1);
#pragma unroll
    for (int ks = 0; ks < 3; ++ks) {
        bf16x8 ap[4];
#pragma unroll
        for (int m = 0; m < 4; ++m)
            ap[m] = (ks < 2 || l4 < 2) ? lv8(&Pw[(m * 16 + l15) * 88 + ks * 32 + l4 * 8])
                                       : zero8();
#pragma unroll
        for (int n = 0; n < 5; ++n) {
            bf16x8 bv = (ks < 2 || l4 < 2) ? lv8(&Vt[(n * 16 + l15) * 88 + ks * 32 + l4 * 8])
                                           : zero8();
#pragma unroll
            for (int m = 0; m < 4; ++m)
                accO[m][n] = __builtin_amdgcn_mfma_f32_16x16x32_bf16(ap[m], bv, accO[m][n], 0, 0, 0);
        }
    }
    __builtin_amdgcn_s_setprio(0);

    // --- stage O in LDS, coalesced write-out ---
    __syncthreads();   // everyone done with P/Vt reads; region becomes O [128][80]
#pragma unroll
    for (int m = 0; m < 4; ++m) {
#pragma unroll
        for (int i = 0; i < 4; ++i) {
            const float inv = 1.f / rs[m][i];
            const int rl = wave * 64 + m * 16 + l4 * 4 + i;
#pragma unroll
            for (int n = 0; n < 5; ++n)
                smem[rl * 80 + n * 16 + l15] = f2b(accO[m][n][i] * inv);
        }
    }
    __syncthreads();
    const size_t obase = (size_t)b * SQ_ + qb;
    for (int idx = tid; idx < 1280; idx += 128) {
        int row = idx / 10, seg = idx % 10;
        *reinterpret_cast<us8*>(&Oa[(obase + row) * E_ + h * DH_ + seg * 8]) =
            *reinterpret_cast<us8*>(&smem[row * 80 + seg * 8]);
    }
}

extern "C" void kernel_launch(void* const* d_in, const int* in_sizes, int n_in,
                              void* d_out, int out_size, void* d_ws, size_t ws_size,
                              hipStream_t stream) {
    const float* x  = (const float*)d_in[0];
    const float* y  = (const float*)d_in[1];
    const float* Wq = (const float*)d_in[2];
    const float* bq = (const float*)d_in[3];
    const float* Wk = (const float*)d_in[4];
    const float* bk = (const float*)d_in[5];
    const float* Wv = (const float*)d_in[6];
    const float* bv = (const float*)d_in[7];
    const float* Wo = (const float*)d_in[8];
    const float* bo = (const float*)d_in[9];
    float* out = (float*)d_out;

    char* ws = (char*)d_ws;
    unsigned short* WqT = (unsigned short*)(ws + 0);         //  819,200 B
    unsigned short* WkT = (unsigned short*)(ws + 819200);    //  983,040 B
    unsigned short* WvT = (unsigned short*)(ws + 1802240);   //  983,040 B
    unsigned short* WoT = (unsigned short*)(ws + 2785280);   //  819,200 B
    unsigned short* Qb  = (unsigned short*)(ws + 3604480);   // 41,943,040 B
    unsigned short* Kb  = (unsigned short*)(ws + 45547520);  //  3,153,920 B
    unsigned short* Vb  = (unsigned short*)(ws + 48701440);  //  3,153,920 B
    unsigned short* Xb  = (unsigned short*)(ws + 51855360);  // 41,943,040 B (big path only)
    const bool big = ws_size >= (size_t)(51855360 + 41943040);

    transpose2_kernel<<<dim3(20, 20, 2), 256, 0, stream>>>(Wq, WqT, Wo, WoT, 640, 640);
    transpose2_kernel<<<dim3(20, 24, 2), 256, 0, stream>>>(Wk, WkT, Wv, WvT, 768, 640);

    if (big) {
        convert_kernel<<<2048, 256, 0, stream>>>(x, Xb, (long)32768 * 640 / 8);
        gemm2<0, false><<<dim3(256, 5), 256, 0, stream>>>(Xb, WqT, bq, Qb, 32768, 640, 640);
    } else {
        gemm2<1, false><<<dim3(256, 5), 256, 0, stream>>>(x, WqT, bq, Qb, 32768, 640, 640);
    }
    gemm_kv<<<dim3(20, 5, 2), 256, 0, stream>>>(y, WkT, bk, Kb, WvT, bv, Vb);

    attn_kernel<<<dim3(8, 8, 32), 128, 0, stream>>>(Qb, Kb, Vb, Qb);

    gemm2<0, true><<<dim3(256, 5), 256, 0, stream>>>(Qb, WoT, bo, out, 32768, 640, 640);
}

// Round 6
// 212.553 us; speedup vs baseline: 1.3046x; 1.0155x over previous
//
#include <hip/hip_runtime.h>
#include <hip/hip_bf16.h>

typedef __bf16 bf16x8 __attribute__((ext_vector_type(8)));
typedef float f32x4 __attribute__((ext_vector_type(4)));
typedef unsigned short us8 __attribute__((ext_vector_type(8)));

#define E_ 640
#define CD_ 768
#define B_ 32
#define SQ_ 1024
#define SKV_ 77
#define H_ 8
#define DH_ 80

typedef __attribute__((address_space(3))) unsigned int as3_u32;
typedef __attribute__((address_space(1))) const unsigned int as1_u32;

__device__ __forceinline__ void gload16(const unsigned short* g, unsigned short* l) {
    __builtin_amdgcn_global_load_lds((as1_u32*)g, (as3_u32*)l, 16, 0, 0);
}

__device__ __forceinline__ float b2f(unsigned short u) {
    unsigned int x = ((unsigned int)u) << 16;
    return __builtin_bit_cast(float, x);
}
__device__ __forceinline__ unsigned short f2b(float f) {
    unsigned int x = __builtin_bit_cast(unsigned int, f);
    x += 0x7fffu + ((x >> 16) & 1u);   // RNE
    return (unsigned short)(x >> 16);
}
__device__ __forceinline__ bf16x8 lv8(const unsigned short* p) {
    return __builtin_bit_cast(bf16x8, *reinterpret_cast<const us8*>(p));
}
__device__ __forceinline__ bf16x8 zero8() {
    us8 z = {0,0,0,0,0,0,0,0};
    return __builtin_bit_cast(bf16x8, z);
}
__device__ __forceinline__ us8 cvt8(const float* s) {
    f32x4 f0 = *reinterpret_cast<const f32x4*>(s);
    f32x4 f1 = *reinterpret_cast<const f32x4*>(s + 4);
    us8 v;
    v[0]=f2b(f0[0]); v[1]=f2b(f0[1]); v[2]=f2b(f0[2]); v[3]=f2b(f0[3]);
    v[4]=f2b(f1[0]); v[5]=f2b(f1[1]); v[6]=f2b(f1[2]); v[7]=f2b(f1[3]);
    return v;
}

// ---------------- transpose+cast pair: two f32 [K][N] -> bf16 [N][K] ----------------
__global__ __launch_bounds__(256) void transpose2_kernel(
    const float* __restrict__ inA, unsigned short* __restrict__ outA,
    const float* __restrict__ inB, unsigned short* __restrict__ outB,
    int K, int N)
{
    const float* in = blockIdx.z ? inB : inA;
    unsigned short* out = blockIdx.z ? outB : outA;
    __shared__ unsigned short t[32][33];
    const int tx = threadIdx.x & 31, ty = threadIdx.x >> 5;
    const int n0 = blockIdx.x * 32, k0 = blockIdx.y * 32;
#pragma unroll
    for (int i = 0; i < 4; ++i)
        t[ty + 8*i][tx] = f2b(in[(size_t)(k0 + ty + 8*i) * N + n0 + tx]);
    __syncthreads();
#pragma unroll
    for (int i = 0; i < 4; ++i)
        out[(size_t)(n0 + ty + 8*i) * K + k0 + tx] = t[tx][ty + 8*i];
}

// ---------------- V transpose: Vb [32*77][640] -> Vt [32*8][80][80] (kv 77..79 zeroed) ----------------
__global__ __launch_bounds__(256) void vtrans_kernel(
    const unsigned short* __restrict__ Vb, unsigned short* __restrict__ Vt)
{
    __shared__ unsigned short Vl[77 * 88 + 8];
    const int b = blockIdx.x, h = blockIdx.y;
    const int tid = threadIdx.x;
    for (int idx = tid; idx < 770; idx += 256) {
        int kv = idx / 10, seg = idx % 10;
        *reinterpret_cast<us8*>(&Vl[kv * 88 + seg * 8]) =
            *reinterpret_cast<const us8*>(&Vb[(size_t)(b * 77 + kv) * 640 + h * 80 + seg * 8]);
    }
    __syncthreads();
    unsigned short* out = Vt + (size_t)(b * 8 + h) * 6400;
    for (int idx = tid; idx < 800; idx += 256) {   // d = idx/10, kv-seg = idx%10
        int d = idx / 10, seg = idx % 10;
        us8 v;
#pragma unroll
        for (int j = 0; j < 8; ++j) {
            int kv = seg * 8 + j;
            v[j] = (kv < 77) ? Vl[kv * 88 + d] : (unsigned short)0;
        }
        *reinterpret_cast<us8*>(&out[d * 80 + seg * 8]) = v;
    }
}

// ---------------- GEMM body: C[M][ldc] = A[M][K] @ Wt^T + bias ----------------
// 2-phase double-buffered K-loop. 32 KB LDS.
template<int AMODE, bool CF32>
__device__ __forceinline__ void gemm_body(
    const void* __restrict__ Ap,
    const unsigned short* __restrict__ Wt,
    const float* __restrict__ bias,
    void* __restrict__ Cp,
    int M, int K, int ldc)
{
    __shared__ __align__(16) unsigned short smem[16384];   // 2 x {As[128*32] | Ws[128*32]}
    const int tid = threadIdx.x, lane = tid & 63, wave = tid >> 6;
    const int wr = (wave >> 1) << 6, wc = (wave & 1) << 6;
    const int m0 = blockIdx.x * 128, n0 = blockIdx.y * 128;
    const int l15 = lane & 15, l4 = lane >> 4;

    const int cw = wave * 64 + lane;
    const unsigned short* gW0 = Wt + (size_t)(n0 + (cw >> 2)) * K + (cw & 3) * 8;
    const unsigned short* gW1 = Wt + (size_t)(n0 + ((cw + 256) >> 2)) * K + ((cw + 256) & 3) * 8;

    const unsigned short* gA0; const unsigned short* gA1;
    const float* fA0; const float* fA1;
    if constexpr (AMODE == 0) {
        gA0 = (const unsigned short*)Ap + (size_t)(m0 + (cw >> 2)) * K + (cw & 3) * 8;
        gA1 = (const unsigned short*)Ap + (size_t)(m0 + ((cw + 256) >> 2)) * K + ((cw + 256) & 3) * 8;
    } else {
        int c0 = tid, c1 = tid + 256;
        int r0 = m0 + (c0 >> 2); if (r0 >= M) r0 = M - 1;
        int r1 = m0 + (c1 >> 2); if (r1 >= M) r1 = M - 1;
        fA0 = (const float*)Ap + (size_t)r0 * K + (c0 & 3) * 8;
        fA1 = (const float*)Ap + (size_t)r1 * K + (c1 & 3) * 8;
    }

    f32x4 acc[4][4];
#pragma unroll
    for (int m = 0; m < 4; ++m)
#pragma unroll
        for (int n = 0; n < 4; ++n)
#pragma unroll
            for (int i = 0; i < 4; ++i) acc[m][n][i] = 0.f;

    auto STAGE = [&](int buf) {
        unsigned short* As = smem + buf * 8192;
        unsigned short* Ws = As + 4096;
        if constexpr (AMODE == 0) {
            gload16(gA0, As + cw * 8);
            gload16(gA1, As + (cw + 256) * 8);
            gA0 += 32; gA1 += 32;
        } else {
            *reinterpret_cast<us8*>(As + tid * 8) = cvt8(fA0);
            *reinterpret_cast<us8*>(As + (tid + 256) * 8) = cvt8(fA1);
            fA0 += 32; fA1 += 32;
        }
        gload16(gW0, Ws + cw * 8);
        gload16(gW1, Ws + (cw + 256) * 8);
        gW0 += 32; gW1 += 32;
    };
    auto COMPUTE = [&](int buf) {
        const unsigned short* As = smem + buf * 8192;
        const unsigned short* Ws = As + 4096;
        bf16x8 a[4], b[4];
#pragma unroll
        for (int m = 0; m < 4; ++m)
            a[m] = lv8(&As[(wr + m * 16 + l15) * 32 + l4 * 8]);
#pragma unroll
        for (int n = 0; n < 4; ++n)
            b[n] = lv8(&Ws[(wc + n * 16 + l15) * 32 + l4 * 8]);
        __builtin_amdgcn_s_setprio(1);
#pragma unroll
        for (int m = 0; m < 4; ++m)
#pragma unroll
            for (int n = 0; n < 4; ++n)
                acc[m][n] = __builtin_amdgcn_mfma_f32_16x16x32_bf16(a[m], b[n], acc[m][n], 0, 0, 0);
        __builtin_amdgcn_s_setprio(0);
    };

    const int nk = K >> 5;   // 20 or 24, always even and >= 4
    STAGE(0);
    __syncthreads();
    for (int kt = 0; kt < nk - 2; kt += 2) {
        STAGE(1);
        COMPUTE(0);
        __syncthreads();
        STAGE(0);
        COMPUTE(1);
        __syncthreads();
    }
    STAGE(1);
    COMPUTE(0);
    __syncthreads();
    COMPUTE(1);

    float bs[4];
#pragma unroll
    for (int n = 0; n < 4; ++n) bs[n] = bias[n0 + wc + n * 16 + l15];

    if constexpr (CF32) {
        float* C = (float*)Cp;
        float* fs = (float*)smem;
#pragma unroll
        for (int p = 0; p < 2; ++p) {
            __syncthreads();
            if (wr == p * 64) {
#pragma unroll
                for (int m = 0; m < 4; ++m)
#pragma unroll
                    for (int n = 0; n < 4; ++n)
#pragma unroll
                        for (int i = 0; i < 4; ++i)
                            fs[(m * 16 + l4 * 4 + i) * 128 + wc + n * 16 + l15] =
                                acc[m][n][i] + bs[n];
            }
            __syncthreads();
#pragma unroll
            for (int r = 0; r < 8; ++r) {
                const int off = (r * 256 + tid) * 4;
                const int row = off >> 7, col = off & 127;
                const int grow = m0 + p * 64 + row;
                if (grow < M)
                    *reinterpret_cast<f32x4*>(&C[(size_t)grow * ldc + n0 + col]) =
                        *reinterpret_cast<const f32x4*>(&fs[off]);
            }
        }
    } else {
        unsigned short* C = (unsigned short*)Cp;
#pragma unroll
        for (int p = 0; p < 2; ++p) {
            __syncthreads();
            if (wr == p * 64) {
#pragma unroll
                for (int m = 0; m < 4; ++m)
#pragma unroll
                    for (int n = 0; n < 4; ++n)
#pragma unroll
                        for (int i = 0; i < 4; ++i)
                            smem[(m * 16 + l4 * 4 + i) * 128 + wc + n * 16 + l15] =
                                f2b(acc[m][n][i] + bs[n]);
            }
            __syncthreads();
#pragma unroll
            for (int r = 0; r < 4; ++r) {
                const int off = (r * 256 + tid) * 8;
                const int row = off >> 7, col = off & 127;
                const int grow = m0 + p * 64 + row;
                if (grow < M)
                    *reinterpret_cast<us8*>(&C[(size_t)grow * ldc + n0 + col]) =
                        *reinterpret_cast<us8*>(&smem[off]);
            }
        }
    }
}

template<int AMODE, bool CF32>
__global__ __launch_bounds__(256) void gemm2(
    const void* __restrict__ Ap, const unsigned short* __restrict__ Wt,
    const float* __restrict__ bias, void* __restrict__ Cp, int M, int K, int ldc)
{
    gemm_body<AMODE, CF32>(Ap, Wt, bias, Cp, M, K, ldc);
}

// fused K-proj + V-proj (blockIdx.z selects)
__global__ __launch_bounds__(256) void gemm_kv(
    const float* __restrict__ y,
    const unsigned short* __restrict__ WkT, const float* __restrict__ bk2, unsigned short* __restrict__ Kb,
    const unsigned short* __restrict__ WvT, const float* __restrict__ bv2, unsigned short* __restrict__ Vb)
{
    const unsigned short* Wt = blockIdx.z ? WvT : WkT;
    const float* bias = blockIdx.z ? bv2 : bk2;
    unsigned short* C = blockIdx.z ? Vb : Kb;
    gemm_body<1, false>(y, Wt, bias, C, 2464, 768, 640);
}

// ---------------- attention: per (128 q-rows, head, batch) ----------------
// No K/V LDS staging: K fragments direct from global (L2-resident), V fragments
// from pre-transposed global Vt. LDS only holds P (per-wave) then O staging.
__global__ __launch_bounds__(128) void attn_kernel(
    const unsigned short* __restrict__ Q,
    const unsigned short* __restrict__ Kp,   // [2464][640]
    const unsigned short* __restrict__ Vt,   // [256][80][80], kv 77..79 zeroed
    unsigned short* __restrict__ Oa)
{
    __shared__ __align__(16) unsigned short smem[11272];  // P [2][64][88] -> O [128][80]
    const int tid = threadIdx.x, lane = tid & 63, wave = tid >> 6;
    const int l15 = lane & 15, l4 = lane >> 4;
    const int qb = blockIdx.x * 128, h = blockIdx.y, b = blockIdx.z;
    const size_t qrow0 = (size_t)b * SQ_ + qb + wave * 64;
    const size_t kbase = (size_t)b * SKV_ * E_ + h * DH_;
    const size_t vbase = (size_t)(b * 8 + h) * 6400;

    // --- Q fragments ---
    bf16x8 aq[3][4];
#pragma unroll
    for (int ks = 0; ks < 3; ++ks) {
        const int d = ks * 32 + l4 * 8;
#pragma unroll
        for (int m = 0; m < 4; ++m)
            aq[ks][m] = (d < 80) ? lv8(&Q[(qrow0 + m * 16 + l15) * E_ + h * DH_ + d]) : zero8();
    }

    // --- scores = Q K^T, K fragments direct from global ---
    f32x4 accS[4][5];
#pragma unroll
    for (int m = 0; m < 4; ++m)
#pragma unroll
        for (int n = 0; n < 5; ++n)
#pragma unroll
            for (int i = 0; i < 4; ++i) accS[m][n][i] = 0.f;

#pragma unroll
    for (int ks = 0; ks < 3; ++ks) {
        const int d = ks * 32 + l4 * 8;
#pragma unroll
        for (int n = 0; n < 5; ++n) {
            const int kv = n * 16 + l15;
            bf16x8 bk = (kv < SKV_ && d < 80) ? lv8(&Kp[kbase + (size_t)kv * E_ + d]) : zero8();
            __builtin_amdgcn_s_setprio(1);
#pragma unroll
            for (int m = 0; m < 4; ++m)
                accS[m][n] = __builtin_amdgcn_mfma_f32_16x16x32_bf16(aq[ks][m], bk, accS[m][n], 0, 0, 0);
            __builtin_amdgcn_s_setprio(0);
        }
    }

    unsigned short* Pw = smem + wave * 5632;   // [64][88]

    // --- softmax ---
    const float scale = 0.11180339887498949f; // 1/sqrt(80)
    float rs[4][4];
#pragma unroll
    for (int m = 0; m < 4; ++m) {
#pragma unroll
        for (int i = 0; i < 4; ++i) {
            float mx = -1e30f;
#pragma unroll
            for (int n = 0; n < 5; ++n) {
                float s = accS[m][n][i] * scale;
                if (n == 4 && l15 >= 13) s = -1e30f;   // kv = 64+l15 >= 77
                accS[m][n][i] = s;
                mx = fmaxf(mx, s);
            }
            mx = fmaxf(mx, __shfl_xor(mx, 1));
            mx = fmaxf(mx, __shfl_xor(mx, 2));
            mx = fmaxf(mx, __shfl_xor(mx, 4));
            mx = fmaxf(mx, __shfl_xor(mx, 8));
            float sum = 0.f;
            const int prow = m * 16 + l4 * 4 + i;
#pragma unroll
            for (int n = 0; n < 5; ++n) {
                float p = __expf(accS[m][n][i] - mx);
                sum += p;
                Pw[prow * 88 + n * 16 + l15] = f2b(p);
            }
            sum += __shfl_xor(sum, 1);
            sum += __shfl_xor(sum, 2);
            sum += __shfl_xor(sum, 4);
            sum += __shfl_xor(sum, 8);
            rs[m][i] = sum;
        }
    }

    // --- out = P V, V fragments direct from global Vt ---
    f32x4 accO[4][5];
#pragma unroll
    for (int m = 0; m < 4; ++m)
#pragma unroll
        for (int n = 0; n < 5; ++n)
#pragma unroll
            for (int i = 0; i < 4; ++i) accO[m][n][i] = 0.f;

#pragma unroll
    for (int ks = 0; ks < 3; ++ks) {
        const int kv = ks * 32 + l4 * 8;
        bf16x8 ap[4];
#pragma unroll
        for (int m = 0; m < 4; ++m)
            ap[m] = (ks < 2 || l4 < 2) ? lv8(&Pw[(m * 16 + l15) * 88 + ks * 32 + l4 * 8])
                                       : zero8();
#pragma unroll
        for (int n = 0; n < 5; ++n) {
            const int d = n * 16 + l15;   // always < 80
            bf16x8 bv = (kv < 80) ? lv8(&Vt[vbase + (size_t)d * 80 + kv]) : zero8();
            __builtin_amdgcn_s_setprio(1);
#pragma unroll
            for (int m = 0; m < 4; ++m)
                accO[m][n] = __builtin_amdgcn_mfma_f32_16x16x32_bf16(ap[m], bv, accO[m][n], 0, 0, 0);
            __builtin_amdgcn_s_setprio(0);
        }
    }

    // --- stage O in LDS, coalesced write-out ---
    __syncthreads();   // all waves done with P region; becomes O [128][80]
#pragma unroll
    for (int m = 0; m < 4; ++m) {
#pragma unroll
        for (int i = 0; i < 4; ++i) {
            const float inv = 1.f / rs[m][i];
            const int rl = wave * 64 + m * 16 + l4 * 4 + i;
#pragma unroll
            for (int n = 0; n < 5; ++n)
                smem[rl * 80 + n * 16 + l15] = f2b(accO[m][n][i] * inv);
        }
    }
    __syncthreads();
    const size_t obase = (size_t)b * SQ_ + qb;
    for (int idx = tid; idx < 1280; idx += 128) {
        int row = idx / 10, seg = idx % 10;
        *reinterpret_cast<us8*>(&Oa[(obase + row) * E_ + h * DH_ + seg * 8]) =
            *reinterpret_cast<us8*>(&smem[row * 80 + seg * 8]);
    }
}

extern "C" void kernel_launch(void* const* d_in, const int* in_sizes, int n_in,
                              void* d_out, int out_size, void* d_ws, size_t ws_size,
                              hipStream_t stream) {
    const float* x  = (const float*)d_in[0];
    const float* y  = (const float*)d_in[1];
    const float* Wq = (const float*)d_in[2];
    const float* bq = (const float*)d_in[3];
    const float* Wk = (const float*)d_in[4];
    const float* bk = (const float*)d_in[5];
    const float* Wv = (const float*)d_in[6];
    const float* bv = (const float*)d_in[7];
    const float* Wo = (const float*)d_in[8];
    const float* bo = (const float*)d_in[9];
    float* out = (float*)d_out;

    char* ws = (char*)d_ws;
    unsigned short* WqT = (unsigned short*)(ws + 0);         //  819,200 B
    unsigned short* WkT = (unsigned short*)(ws + 819200);    //  983,040 B
    unsigned short* WvT = (unsigned short*)(ws + 1802240);   //  983,040 B
    unsigned short* WoT = (unsigned short*)(ws + 2785280);   //  819,200 B
    unsigned short* Qb  = (unsigned short*)(ws + 3604480);   // 41,943,040 B
    unsigned short* Kb  = (unsigned short*)(ws + 45547520);  //  3,153,920 B
    unsigned short* Vb  = (unsigned short*)(ws + 48701440);  //  3,153,920 B
    unsigned short* Vtb = (unsigned short*)(ws + 51855360);  //  6,553,600 B (proven available)

    transpose2_kernel<<<dim3(20, 20, 2), 256, 0, stream>>>(Wq, WqT, Wo, WoT, 640, 640);
    transpose2_kernel<<<dim3(20, 24, 2), 256, 0, stream>>>(Wk, WkT, Wv, WvT, 768, 640);

    gemm2<1, false><<<dim3(256, 5), 256, 0, stream>>>(x, WqT, bq, Qb, 32768, 640, 640);
    gemm_kv<<<dim3(20, 5, 2), 256, 0, stream>>>(y, WkT, bk, Kb, WvT, bv, Vb);
    vtrans_kernel<<<dim3(32, 8), 256, 0, stream>>>(Vb, Vtb);

    attn_kernel<<<dim3(8, 8, 32), 128, 0, stream>>>(Qb, Kb, Vtb, Qb);

    gemm2<0, true><<<dim3(256, 5), 256, 0, stream>>>(Qb, WoT, bo, out, 32768, 640, 640);
}

// Round 7
// 190.645 us; speedup vs baseline: 1.4545x; 1.1149x over previous
//
#include <hip/hip_runtime.h>
#include <hip/hip_bf16.h>

typedef __bf16 bf16x8 __attribute__((ext_vector_type(8)));
typedef float f32x4 __attribute__((ext_vector_type(4)));
typedef unsigned short us8 __attribute__((ext_vector_type(8)));

#define E_ 640
#define CD_ 768
#define B_ 32
#define SQ_ 1024
#define SKV_ 77
#define H_ 8
#define DH_ 80

typedef __attribute__((address_space(3))) unsigned int as3_u32;
typedef __attribute__((address_space(1))) const unsigned int as1_u32;

__device__ __forceinline__ void gload16(const unsigned short* g, unsigned short* l) {
    __builtin_amdgcn_global_load_lds((as1_u32*)g, (as3_u32*)l, 16, 0, 0);
}

__device__ __forceinline__ float b2f(unsigned short u) {
    unsigned int x = ((unsigned int)u) << 16;
    return __builtin_bit_cast(float, x);
}
__device__ __forceinline__ unsigned short f2b(float f) {
    unsigned int x = __builtin_bit_cast(unsigned int, f);
    x += 0x7fffu + ((x >> 16) & 1u);   // RNE
    return (unsigned short)(x >> 16);
}
__device__ __forceinline__ bf16x8 lv8(const unsigned short* p) {
    return __builtin_bit_cast(bf16x8, *reinterpret_cast<const us8*>(p));
}
__device__ __forceinline__ bf16x8 zero8() {
    us8 z = {0,0,0,0,0,0,0,0};
    return __builtin_bit_cast(bf16x8, z);
}
__device__ __forceinline__ us8 cvt8(const float* s) {
    f32x4 f0 = *reinterpret_cast<const f32x4*>(s);
    f32x4 f1 = *reinterpret_cast<const f32x4*>(s + 4);
    us8 v;
    v[0]=f2b(f0[0]); v[1]=f2b(f0[1]); v[2]=f2b(f0[2]); v[3]=f2b(f0[3]);
    v[4]=f2b(f1[0]); v[5]=f2b(f1[1]); v[6]=f2b(f1[2]); v[7]=f2b(f1[3]);
    return v;
}

// ---------------- fused prep: 4 weight transposes + x->bf16 convert ----------------
__device__ __forceinline__ void transpose_body(
    const float* __restrict__ in, unsigned short* __restrict__ out,
    int K, int N, int bx, int by, unsigned short (*t)[33])
{
    const int tx = threadIdx.x & 31, ty = threadIdx.x >> 5;
    const int n0 = bx * 32, k0 = by * 32;
#pragma unroll
    for (int i = 0; i < 4; ++i)
        t[ty + 8*i][tx] = f2b(in[(size_t)(k0 + ty + 8*i) * N + n0 + tx]);
    __syncthreads();
#pragma unroll
    for (int i = 0; i < 4; ++i)
        out[(size_t)(n0 + ty + 8*i) * K + k0 + tx] = t[tx][ty + 8*i];
}

__global__ __launch_bounds__(256) void fused_prep(
    const float* __restrict__ Wq, unsigned short* __restrict__ WqT,
    const float* __restrict__ Wo, unsigned short* __restrict__ WoT,
    const float* __restrict__ Wk, unsigned short* __restrict__ WkT,
    const float* __restrict__ Wv, unsigned short* __restrict__ WvT,
    const float* __restrict__ x, unsigned short* __restrict__ Xb)
{
    __shared__ unsigned short t[32][33];
    const int id = blockIdx.x;
    if (id < 800) {                         // Wq / Wo : [640][640]
        int z = id / 400, rem = id % 400;
        transpose_body(z ? Wo : Wq, z ? WoT : WqT, 640, 640, rem % 20, rem / 20, t);
    } else if (id < 1760) {                 // Wk / Wv : [768][640]
        int id2 = id - 800, z = id2 / 480, rem = id2 % 480;
        transpose_body(z ? Wv : Wk, z ? WvT : WkT, 768, 640, rem % 20, rem / 20, t);
    } else {                                // convert x (grid-stride, 2048 blocks)
        long i = (long)(id - 1760) * 256 + threadIdx.x;
        const long stride = 2048L * 256;
        for (const long n8 = 2621440L; i < n8; i += stride)
            *reinterpret_cast<us8*>(Xb + i * 8) = cvt8(x + i * 8);
    }
}

// ---------------- GEMM body: C[M][ldc] = A[M][K] @ Wt^T + bias ----------------
// 2-phase double-buffered K-loop. 32 KB LDS.
template<int AMODE, bool CF32>
__device__ __forceinline__ void gemm_body(
    const void* __restrict__ Ap,
    const unsigned short* __restrict__ Wt,
    const float* __restrict__ bias,
    void* __restrict__ Cp,
    int M, int K, int ldc, int m0, int n0)
{
    __shared__ __align__(16) unsigned short smem[16384];   // 2 x {As[128*32] | Ws[128*32]}
    const int tid = threadIdx.x, lane = tid & 63, wave = tid >> 6;
    const int wr = (wave >> 1) << 6, wc = (wave & 1) << 6;
    const int l15 = lane & 15, l4 = lane >> 4;

    const int cw = wave * 64 + lane;
    const unsigned short* gW0 = Wt + (size_t)(n0 + (cw >> 2)) * K + (cw & 3) * 8;
    const unsigned short* gW1 = Wt + (size_t)(n0 + ((cw + 256) >> 2)) * K + ((cw + 256) & 3) * 8;

    const unsigned short* gA0; const unsigned short* gA1;
    const float* fA0; const float* fA1;
    if constexpr (AMODE == 0) {
        gA0 = (const unsigned short*)Ap + (size_t)(m0 + (cw >> 2)) * K + (cw & 3) * 8;
        gA1 = (const unsigned short*)Ap + (size_t)(m0 + ((cw + 256) >> 2)) * K + ((cw + 256) & 3) * 8;
    } else {
        int c0 = tid, c1 = tid + 256;
        int r0 = m0 + (c0 >> 2); if (r0 >= M) r0 = M - 1;
        int r1 = m0 + (c1 >> 2); if (r1 >= M) r1 = M - 1;
        fA0 = (const float*)Ap + (size_t)r0 * K + (c0 & 3) * 8;
        fA1 = (const float*)Ap + (size_t)r1 * K + (c1 & 3) * 8;
    }

    f32x4 acc[4][4];
#pragma unroll
    for (int m = 0; m < 4; ++m)
#pragma unroll
        for (int n = 0; n < 4; ++n)
#pragma unroll
            for (int i = 0; i < 4; ++i) acc[m][n][i] = 0.f;

    auto STAGE = [&](int buf) {
        unsigned short* As = smem + buf * 8192;
        unsigned short* Ws = As + 4096;
        if constexpr (AMODE == 0) {
            gload16(gA0, As + cw * 8);
            gload16(gA1, As + (cw + 256) * 8);
            gA0 += 32; gA1 += 32;
        } else {
            *reinterpret_cast<us8*>(As + tid * 8) = cvt8(fA0);
            *reinterpret_cast<us8*>(As + (tid + 256) * 8) = cvt8(fA1);
            fA0 += 32; fA1 += 32;
        }
        gload16(gW0, Ws + cw * 8);
        gload16(gW1, Ws + (cw + 256) * 8);
        gW0 += 32; gW1 += 32;
    };
    auto COMPUTE = [&](int buf) {
        const unsigned short* As = smem + buf * 8192;
        const unsigned short* Ws = As + 4096;
        bf16x8 a[4], b[4];
#pragma unroll
        for (int m = 0; m < 4; ++m)
            a[m] = lv8(&As[(wr + m * 16 + l15) * 32 + l4 * 8]);
#pragma unroll
        for (int n = 0; n < 4; ++n)
            b[n] = lv8(&Ws[(wc + n * 16 + l15) * 32 + l4 * 8]);
        __builtin_amdgcn_s_setprio(1);
#pragma unroll
        for (int m = 0; m < 4; ++m)
#pragma unroll
            for (int n = 0; n < 4; ++n)
                acc[m][n] = __builtin_amdgcn_mfma_f32_16x16x32_bf16(a[m], b[n], acc[m][n], 0, 0, 0);
        __builtin_amdgcn_s_setprio(0);
    };

    const int nk = K >> 5;   // 20 or 24, always even and >= 4
    STAGE(0);
    __syncthreads();
    for (int kt = 0; kt < nk - 2; kt += 2) {
        STAGE(1);
        COMPUTE(0);
        __syncthreads();
        STAGE(0);
        COMPUTE(1);
        __syncthreads();
    }
    STAGE(1);
    COMPUTE(0);
    __syncthreads();
    COMPUTE(1);

    float bs[4];
#pragma unroll
    for (int n = 0; n < 4; ++n) bs[n] = bias[n0 + wc + n * 16 + l15];

    if constexpr (CF32) {
        float* C = (float*)Cp;
        float* fs = (float*)smem;
#pragma unroll
        for (int p = 0; p < 2; ++p) {
            __syncthreads();
            if (wr == p * 64) {
#pragma unroll
                for (int m = 0; m < 4; ++m)
#pragma unroll
                    for (int n = 0; n < 4; ++n)
#pragma unroll
                        for (int i = 0; i < 4; ++i)
                            fs[(m * 16 + l4 * 4 + i) * 128 + wc + n * 16 + l15] =
                                acc[m][n][i] + bs[n];
            }
            __syncthreads();
#pragma unroll
            for (int r = 0; r < 8; ++r) {
                const int off = (r * 256 + tid) * 4;
                const int row = off >> 7, col = off & 127;
                const int grow = m0 + p * 64 + row;
                if (grow < M)
                    *reinterpret_cast<f32x4*>(&C[(size_t)grow * ldc + n0 + col]) =
                        *reinterpret_cast<const f32x4*>(&fs[off]);
            }
        }
    } else {
        unsigned short* C = (unsigned short*)Cp;
#pragma unroll
        for (int p = 0; p < 2; ++p) {
            __syncthreads();
            if (wr == p * 64) {
#pragma unroll
                for (int m = 0; m < 4; ++m)
#pragma unroll
                    for (int n = 0; n < 4; ++n)
#pragma unroll
                        for (int i = 0; i < 4; ++i)
                            smem[(m * 16 + l4 * 4 + i) * 128 + wc + n * 16 + l15] =
                                f2b(acc[m][n][i] + bs[n]);
            }
            __syncthreads();
#pragma unroll
            for (int r = 0; r < 4; ++r) {
                const int off = (r * 256 + tid) * 8;
                const int row = off >> 7, col = off & 127;
                const int grow = m0 + p * 64 + row;
                if (grow < M)
                    *reinterpret_cast<us8*>(&C[(size_t)grow * ldc + n0 + col]) =
                        *reinterpret_cast<us8*>(&smem[off]);
            }
        }
    }
}

template<int AMODE, bool CF32>
__global__ __launch_bounds__(256) void gemm2(
    const void* __restrict__ Ap, const unsigned short* __restrict__ Wt,
    const float* __restrict__ bias, void* __restrict__ Cp, int M, int K, int ldc)
{
    gemm_body<AMODE, CF32>(Ap, Wt, bias, Cp, M, K, ldc, blockIdx.x * 128, blockIdx.y * 128);
}

// ---------------- fused Q-proj (bf16 Xb) + K-proj + V-proj (fp32 y) ----------------
// blocks [0,200): KV (z = id/100); blocks [200, 1480): Q
__global__ __launch_bounds__(256) void fused_qkv(
    const unsigned short* __restrict__ Xb, const unsigned short* __restrict__ WqT,
    const float* __restrict__ bq, unsigned short* __restrict__ Qb,
    const float* __restrict__ y,
    const unsigned short* __restrict__ WkT, const float* __restrict__ bk2, unsigned short* __restrict__ Kb,
    const unsigned short* __restrict__ WvT, const float* __restrict__ bv2, unsigned short* __restrict__ Vb)
{
    const int id = blockIdx.x;
    if (id < 200) {
        int z = id / 100, rem = id % 100;
        int m0 = (rem / 5) * 128, n0 = (rem % 5) * 128;
        if (z == 0) gemm_body<1, false>(y, WkT, bk2, Kb, 2464, 768, 640, m0, n0);
        else        gemm_body<1, false>(y, WvT, bv2, Vb, 2464, 768, 640, m0, n0);
    } else {
        int rem = id - 200;
        int m0 = (rem / 5) * 128, n0 = (rem % 5) * 128;
        gemm_body<0, false>(Xb, WqT, bq, Qb, 32768, 640, 640, m0, n0);
    }
}

// ---------------- V transpose: Vb [32*77][640] -> Vt [32*8][80][80] (kv 77..79 zeroed) ----------------
__global__ __launch_bounds__(256) void vtrans_kernel(
    const unsigned short* __restrict__ Vb, unsigned short* __restrict__ Vt)
{
    __shared__ unsigned short Vl[77 * 88 + 8];
    const int b = blockIdx.x, h = blockIdx.y;
    const int tid = threadIdx.x;
    for (int idx = tid; idx < 770; idx += 256) {
        int kv = idx / 10, seg = idx % 10;
        *reinterpret_cast<us8*>(&Vl[kv * 88 + seg * 8]) =
            *reinterpret_cast<const us8*>(&Vb[(size_t)(b * 77 + kv) * 640 + h * 80 + seg * 8]);
    }
    __syncthreads();
    unsigned short* out = Vt + (size_t)(b * 8 + h) * 6400;
    for (int idx = tid; idx < 800; idx += 256) {
        int d = idx / 10, seg = idx % 10;
        us8 v;
#pragma unroll
        for (int j = 0; j < 8; ++j) {
            int kv = seg * 8 + j;
            v[j] = (kv < 77) ? Vl[kv * 88 + d] : (unsigned short)0;
        }
        *reinterpret_cast<us8*>(&out[d * 80 + seg * 8]) = v;
    }
}

// ---------------- attention: per (128 q-rows, head, batch) ----------------
// K fragments direct from global (L2-resident), V from pre-transposed Vt.
// LDS only holds P (per-wave) then O staging.
__global__ __launch_bounds__(128) void attn_kernel(
    const unsigned short* __restrict__ Q,
    const unsigned short* __restrict__ Kp,   // [2464][640]
    const unsigned short* __restrict__ Vt,   // [256][80][80], kv 77..79 zeroed
    unsigned short* __restrict__ Oa)
{
    __shared__ __align__(16) unsigned short smem[11272];  // P [2][64][88] -> O [128][80]
    const int tid = threadIdx.x, lane = tid & 63, wave = tid >> 6;
    const int l15 = lane & 15, l4 = lane >> 4;
    const int qb = blockIdx.x * 128, h = blockIdx.y, b = blockIdx.z;
    const size_t qrow0 = (size_t)b * SQ_ + qb + wave * 64;
    const size_t kbase = (size_t)b * SKV_ * E_ + h * DH_;
    const size_t vbase = (size_t)(b * 8 + h) * 6400;

    // --- Q fragments ---
    bf16x8 aq[3][4];
#pragma unroll
    for (int ks = 0; ks < 3; ++ks) {
        const int d = ks * 32 + l4 * 8;
#pragma unroll
        for (int m = 0; m < 4; ++m)
            aq[ks][m] = (d < 80) ? lv8(&Q[(qrow0 + m * 16 + l15) * E_ + h * DH_ + d]) : zero8();
    }

    // --- scores = Q K^T, K fragments batched per k-step ---
    f32x4 accS[4][5];
#pragma unroll
    for (int m = 0; m < 4; ++m)
#pragma unroll
        for (int n = 0; n < 5; ++n)
#pragma unroll
            for (int i = 0; i < 4; ++i) accS[m][n][i] = 0.f;

#pragma unroll
    for (int ks = 0; ks < 3; ++ks) {
        const int d = ks * 32 + l4 * 8;
        bf16x8 bk[5];
#pragma unroll
        for (int n = 0; n < 5; ++n) {
            const int kv = n * 16 + l15;
            bk[n] = (kv < SKV_ && d < 80) ? lv8(&Kp[kbase + (size_t)kv * E_ + d]) : zero8();
        }
        __builtin_amdgcn_s_setprio(1);
#pragma unroll
        for (int n = 0; n < 5; ++n)
#pragma unroll
            for (int m = 0; m < 4; ++m)
                accS[m][n] = __builtin_amdgcn_mfma_f32_16x16x32_bf16(aq[ks][m], bk[n], accS[m][n], 0, 0, 0);
        __builtin_amdgcn_s_setprio(0);
    }

    unsigned short* Pw = smem + wave * 5632;   // [64][88]

    // --- softmax ---
    const float scale = 0.11180339887498949f; // 1/sqrt(80)
    float rs[4][4];
#pragma unroll
    for (int m = 0; m < 4; ++m) {
#pragma unroll
        for (int i = 0; i < 4; ++i) {
            float mx = -1e30f;
#pragma unroll
            for (int n = 0; n < 5; ++n) {
                float s = accS[m][n][i] * scale;
                if (n == 4 && l15 >= 13) s = -1e30f;   // kv = 64+l15 >= 77
                accS[m][n][i] = s;
                mx = fmaxf(mx, s);
            }
            mx = fmaxf(mx, __shfl_xor(mx, 1));
            mx = fmaxf(mx, __shfl_xor(mx, 2));
            mx = fmaxf(mx, __shfl_xor(mx, 4));
            mx = fmaxf(mx, __shfl_xor(mx, 8));
            float sum = 0.f;
            const int prow = m * 16 + l4 * 4 + i;
#pragma unroll
            for (int n = 0; n < 5; ++n) {
                float p = __expf(accS[m][n][i] - mx);
                sum += p;
                Pw[prow * 88 + n * 16 + l15] = f2b(p);
            }
            sum += __shfl_xor(sum, 1);
            sum += __shfl_xor(sum, 2);
            sum += __shfl_xor(sum, 4);
            sum += __shfl_xor(sum, 8);
            rs[m][i] = sum;
        }
    }

    // --- out = P V, fragments batched per k-step ---
    f32x4 accO[4][5];
#pragma unroll
    for (int m = 0; m < 4; ++m)
#pragma unroll
        for (int n = 0; n < 5; ++n)
#pragma unroll
            for (int i = 0; i < 4; ++i) accO[m][n][i] = 0.f;

#pragma unroll
    for (int ks = 0; ks < 3; ++ks) {
        const int kv = ks * 32 + l4 * 8;
        bf16x8 ap[4], bv[5];
#pragma unroll
        for (int m = 0; m < 4; ++m)
            ap[m] = (ks < 2 || l4 < 2) ? lv8(&Pw[(m * 16 + l15) * 88 + ks * 32 + l4 * 8])
                                       : zero8();
#pragma unroll
        for (int n = 0; n < 5; ++n) {
            const int d = n * 16 + l15;   // always < 80
            bv[n] = (kv < 80) ? lv8(&Vt[vbase + (size_t)d * 80 + kv]) : zero8();
        }
        __builtin_amdgcn_s_setprio(1);
#pragma unroll
        for (int n = 0; n < 5; ++n)
#pragma unroll
            for (int m = 0; m < 4; ++m)
                accO[m][n] = __builtin_amdgcn_mfma_f32_16x16x32_bf16(ap[m], bv[n], accO[m][n], 0, 0, 0);
        __builtin_amdgcn_s_setprio(0);
    }

    // --- stage O in LDS, coalesced write-out ---
    __syncthreads();   // all waves done with P region; becomes O [128][80]
#pragma unroll
    for (int m = 0; m < 4; ++m) {
#pragma unroll
        for (int i = 0; i < 4; ++i) {
            const float inv = 1.f / rs[m][i];
            const int rl = wave * 64 + m * 16 + l4 * 4 + i;
#pragma unroll
            for (int n = 0; n < 5; ++n)
                smem[rl * 80 + n * 16 + l15] = f2b(accO[m][n][i] * inv);
        }
    }
    __syncthreads();
    const size_t obase = (size_t)b * SQ_ + qb;
    for (int idx = tid; idx < 1280; idx += 128) {
        int row = idx / 10, seg = idx % 10;
        *reinterpret_cast<us8*>(&Oa[(obase + row) * E_ + h * DH_ + seg * 8]) =
            *reinterpret_cast<us8*>(&smem[row * 80 + seg * 8]);
    }
}

extern "C" void kernel_launch(void* const* d_in, const int* in_sizes, int n_in,
                              void* d_out, int out_size, void* d_ws, size_t ws_size,
                              hipStream_t stream) {
    const float* x  = (const float*)d_in[0];
    const float* y  = (const float*)d_in[1];
    const float* Wq = (const float*)d_in[2];
    const float* bq = (const float*)d_in[3];
    const float* Wk = (const float*)d_in[4];
    const float* bk = (const float*)d_in[5];
    const float* Wv = (const float*)d_in[6];
    const float* bv = (const float*)d_in[7];
    const float* Wo = (const float*)d_in[8];
    const float* bo = (const float*)d_in[9];
    float* out = (float*)d_out;

    char* ws = (char*)d_ws;
    unsigned short* WqT = (unsigned short*)(ws + 0);         //  819,200 B
    unsigned short* WkT = (unsigned short*)(ws + 819200);    //  983,040 B
    unsigned short* WvT = (unsigned short*)(ws + 1802240);   //  983,040 B
    unsigned short* WoT = (unsigned short*)(ws + 2785280);   //  819,200 B
    unsigned short* Qb  = (unsigned short*)(ws + 3604480);   // 41,943,040 B
    unsigned short* Kb  = (unsigned short*)(ws + 45547520);  //  3,153,920 B
    unsigned short* Vb  = (unsigned short*)(ws + 48701440);  //  3,153,920 B
    unsigned short* Xb  = (unsigned short*)(ws + 51855360);  // 41,943,040 B (dead after fused_qkv)
    unsigned short* Vtb = (unsigned short*)(ws + 51855360);  //  6,553,600 B (aliases Xb)
    // peak footprint: 93,798,400 B (proven available in round 4)

    fused_prep<<<3808, 256, 0, stream>>>(Wq, WqT, Wo, WoT, Wk, WkT, Wv, WvT, x, Xb);
    fused_qkv<<<1480, 256, 0, stream>>>(Xb, WqT, bq, Qb, y, WkT, bk, Kb, WvT, bv, Vb);
    vtrans_kernel<<<dim3(32, 8), 256, 0, stream>>>(Vb, Vtb);
    attn_kernel<<<dim3(8, 8, 32), 128, 0, stream>>>(Qb, Kb, Vtb, Qb);
    gemm2<0, true><<<dim3(256, 5), 256, 0, stream>>>(Qb, WoT, bo, out, 32768, 640, 640);
}

// Round 8
// 174.541 us; speedup vs baseline: 1.5887x; 1.0923x over previous
//
#include <hip/hip_runtime.h>
#include <hip/hip_bf16.h>

typedef __bf16 bf16x8 __attribute__((ext_vector_type(8)));
typedef float f32x4 __attribute__((ext_vector_type(4)));
typedef unsigned short us8 __attribute__((ext_vector_type(8)));

#define E_ 640
#define CD_ 768
#define B_ 32
#define SQ_ 1024
#define SKV_ 77
#define H_ 8
#define DH_ 80

typedef __attribute__((address_space(3))) unsigned int as3_u32;
typedef __attribute__((address_space(1))) const unsigned int as1_u32;

__device__ __forceinline__ void gload16(const unsigned short* g, unsigned short* l) {
    __builtin_amdgcn_global_load_lds((as1_u32*)g, (as3_u32*)l, 16, 0, 0);
}

__device__ __forceinline__ float b2f(unsigned short u) {
    unsigned int x = ((unsigned int)u) << 16;
    return __builtin_bit_cast(float, x);
}
__device__ __forceinline__ unsigned short f2b(float f) {
    unsigned int x = __builtin_bit_cast(unsigned int, f);
    x += 0x7fffu + ((x >> 16) & 1u);   // RNE
    return (unsigned short)(x >> 16);
}
__device__ __forceinline__ bf16x8 lv8(const unsigned short* p) {
    return __builtin_bit_cast(bf16x8, *reinterpret_cast<const us8*>(p));
}
__device__ __forceinline__ bf16x8 zero8() {
    us8 z = {0,0,0,0,0,0,0,0};
    return __builtin_bit_cast(bf16x8, z);
}
__device__ __forceinline__ us8 cvt8(const float* s) {
    f32x4 f0 = *reinterpret_cast<const f32x4*>(s);
    f32x4 f1 = *reinterpret_cast<const f32x4*>(s + 4);
    us8 v;
    v[0]=f2b(f0[0]); v[1]=f2b(f0[1]); v[2]=f2b(f0[2]); v[3]=f2b(f0[3]);
    v[4]=f2b(f1[0]); v[5]=f2b(f1[1]); v[6]=f2b(f1[2]); v[7]=f2b(f1[3]);
    return v;
}

// ---------------- fused prep: 4 weight transposes + x->bf16 convert ----------------
__device__ __forceinline__ void transpose_body(
    const float* __restrict__ in, unsigned short* __restrict__ out,
    int K, int N, int bx, int by, unsigned short (*t)[33])
{
    const int tx = threadIdx.x & 31, ty = threadIdx.x >> 5;
    const int n0 = bx * 32, k0 = by * 32;
#pragma unroll
    for (int i = 0; i < 4; ++i)
        t[ty + 8*i][tx] = f2b(in[(size_t)(k0 + ty + 8*i) * N + n0 + tx]);
    __syncthreads();
#pragma unroll
    for (int i = 0; i < 4; ++i)
        out[(size_t)(n0 + ty + 8*i) * K + k0 + tx] = t[tx][ty + 8*i];
}

__global__ __launch_bounds__(256) void fused_prep(
    const float* __restrict__ Wq, unsigned short* __restrict__ WqT,
    const float* __restrict__ Wo, unsigned short* __restrict__ WoT,
    const float* __restrict__ Wk, unsigned short* __restrict__ WkT,
    const float* __restrict__ Wv, unsigned short* __restrict__ WvT,
    const float* __restrict__ x, unsigned short* __restrict__ Xb)
{
    __shared__ unsigned short t[32][33];
    const int id = blockIdx.x;
    if (id < 800) {                         // Wq / Wo : [640][640]
        int z = id / 400, rem = id % 400;
        transpose_body(z ? Wo : Wq, z ? WoT : WqT, 640, 640, rem % 20, rem / 20, t);
    } else if (id < 1760) {                 // Wk / Wv : [768][640]
        int id2 = id - 800, z = id2 / 480, rem = id2 % 480;
        transpose_body(z ? Wv : Wk, z ? WvT : WkT, 768, 640, rem % 20, rem / 20, t);
    } else {                                // convert x (grid-stride, 2048 blocks)
        long i = (long)(id - 1760) * 256 + threadIdx.x;
        const long stride = 2048L * 256;
        for (const long n8 = 2621440L; i < n8; i += stride)
            *reinterpret_cast<us8*>(Xb + i * 8) = cvt8(x + i * 8);
    }
}

// ---------------- GEMM body: C[M][ldc] = A[M][K] @ Wt^T + bias ----------------
// 2-phase double-buffered K-loop. Caller provides the 32 KB LDS buffer
// (single allocation shared across template instantiations in a kernel).
template<int AMODE, bool CF32>
__device__ __forceinline__ void gemm_body(
    const void* __restrict__ Ap,
    const unsigned short* __restrict__ Wt,
    const float* __restrict__ bias,
    void* __restrict__ Cp,
    int M, int K, int ldc, int m0, int n0,
    unsigned short* smem)
{
    const int tid = threadIdx.x, lane = tid & 63, wave = tid >> 6;
    const int wr = (wave >> 1) << 6, wc = (wave & 1) << 6;
    const int l15 = lane & 15, l4 = lane >> 4;

    const int cw = wave * 64 + lane;
    const unsigned short* gW0 = Wt + (size_t)(n0 + (cw >> 2)) * K + (cw & 3) * 8;
    const unsigned short* gW1 = Wt + (size_t)(n0 + ((cw + 256) >> 2)) * K + ((cw + 256) & 3) * 8;

    const unsigned short* gA0; const unsigned short* gA1;
    const float* fA0; const float* fA1;
    if constexpr (AMODE == 0) {
        gA0 = (const unsigned short*)Ap + (size_t)(m0 + (cw >> 2)) * K + (cw & 3) * 8;
        gA1 = (const unsigned short*)Ap + (size_t)(m0 + ((cw + 256) >> 2)) * K + ((cw + 256) & 3) * 8;
    } else {
        int c0 = tid, c1 = tid + 256;
        int r0 = m0 + (c0 >> 2); if (r0 >= M) r0 = M - 1;
        int r1 = m0 + (c1 >> 2); if (r1 >= M) r1 = M - 1;
        fA0 = (const float*)Ap + (size_t)r0 * K + (c0 & 3) * 8;
        fA1 = (const float*)Ap + (size_t)r1 * K + (c1 & 3) * 8;
    }

    f32x4 acc[4][4];
#pragma unroll
    for (int m = 0; m < 4; ++m)
#pragma unroll
        for (int n = 0; n < 4; ++n)
#pragma unroll
            for (int i = 0; i < 4; ++i) acc[m][n][i] = 0.f;

    auto STAGE = [&](int buf) {
        unsigned short* As = smem + buf * 8192;
        unsigned short* Ws = As + 4096;
        if constexpr (AMODE == 0) {
            gload16(gA0, As + cw * 8);
            gload16(gA1, As + (cw + 256) * 8);
            gA0 += 32; gA1 += 32;
        } else {
            *reinterpret_cast<us8*>(As + tid * 8) = cvt8(fA0);
            *reinterpret_cast<us8*>(As + (tid + 256) * 8) = cvt8(fA1);
            fA0 += 32; fA1 += 32;
        }
        gload16(gW0, Ws + cw * 8);
        gload16(gW1, Ws + (cw + 256) * 8);
        gW0 += 32; gW1 += 32;
    };
    auto COMPUTE = [&](int buf) {
        const unsigned short* As = smem + buf * 8192;
        const unsigned short* Ws = As + 4096;
        bf16x8 a[4], b[4];
#pragma unroll
        for (int m = 0; m < 4; ++m)
            a[m] = lv8(&As[(wr + m * 16 + l15) * 32 + l4 * 8]);
#pragma unroll
        for (int n = 0; n < 4; ++n)
            b[n] = lv8(&Ws[(wc + n * 16 + l15) * 32 + l4 * 8]);
        __builtin_amdgcn_s_setprio(1);
#pragma unroll
        for (int m = 0; m < 4; ++m)
#pragma unroll
            for (int n = 0; n < 4; ++n)
                acc[m][n] = __builtin_amdgcn_mfma_f32_16x16x32_bf16(a[m], b[n], acc[m][n], 0, 0, 0);
        __builtin_amdgcn_s_setprio(0);
    };

    const int nk = K >> 5;   // 20 or 24, always even and >= 4
    STAGE(0);
    __syncthreads();
    for (int kt = 0; kt < nk - 2; kt += 2) {
        STAGE(1);
        COMPUTE(0);
        __syncthreads();
        STAGE(0);
        COMPUTE(1);
        __syncthreads();
    }
    STAGE(1);
    COMPUTE(0);
    __syncthreads();
    COMPUTE(1);

    float bs[4];
#pragma unroll
    for (int n = 0; n < 4; ++n) bs[n] = bias[n0 + wc + n * 16 + l15];

    if constexpr (CF32) {
        float* C = (float*)Cp;
        float* fs = (float*)smem;
#pragma unroll
        for (int p = 0; p < 2; ++p) {
            __syncthreads();
            if (wr == p * 64) {
#pragma unroll
                for (int m = 0; m < 4; ++m)
#pragma unroll
                    for (int n = 0; n < 4; ++n)
#pragma unroll
                        for (int i = 0; i < 4; ++i)
                            fs[(m * 16 + l4 * 4 + i) * 128 + wc + n * 16 + l15] =
                                acc[m][n][i] + bs[n];
            }
            __syncthreads();
#pragma unroll
            for (int r = 0; r < 8; ++r) {
                const int off = (r * 256 + tid) * 4;
                const int row = off >> 7, col = off & 127;
                const int grow = m0 + p * 64 + row;
                if (grow < M)
                    *reinterpret_cast<f32x4*>(&C[(size_t)grow * ldc + n0 + col]) =
                        *reinterpret_cast<const f32x4*>(&fs[off]);
            }
        }
    } else {
        unsigned short* C = (unsigned short*)Cp;
#pragma unroll
        for (int p = 0; p < 2; ++p) {
            __syncthreads();
            if (wr == p * 64) {
#pragma unroll
                for (int m = 0; m < 4; ++m)
#pragma unroll
                    for (int n = 0; n < 4; ++n)
#pragma unroll
                        for (int i = 0; i < 4; ++i)
                            smem[(m * 16 + l4 * 4 + i) * 128 + wc + n * 16 + l15] =
                                f2b(acc[m][n][i] + bs[n]);
            }
            __syncthreads();
#pragma unroll
            for (int r = 0; r < 4; ++r) {
                const int off = (r * 256 + tid) * 8;
                const int row = off >> 7, col = off & 127;
                const int grow = m0 + p * 64 + row;
                if (grow < M)
                    *reinterpret_cast<us8*>(&C[(size_t)grow * ldc + n0 + col]) =
                        *reinterpret_cast<us8*>(&smem[off]);
            }
        }
    }
}

// ---------------- O-proj: 1-D grid with XCD-chunked swizzle (1280 % 8 == 0) ----------------
__global__ __launch_bounds__(256) void gemm_o(
    const unsigned short* __restrict__ Ap, const unsigned short* __restrict__ Wt,
    const float* __restrict__ bias, float* __restrict__ Cp)
{
    __shared__ __align__(16) unsigned short smem[16384];
    const int orig = blockIdx.x;
    const int wgid = (orig & 7) * 160 + (orig >> 3);
    gemm_body<0, true>(Ap, Wt, bias, Cp, 32768, 640, 640, (wgid / 5) * 128, (wgid % 5) * 128, smem);
}

// ---------------- fused Q-proj (bf16 Xb) + K-proj + V-proj (fp32 y) ----------------
// blocks [0,200): KV (z = id/100); blocks [200, 1480): Q with XCD swizzle
__global__ __launch_bounds__(256) void fused_qkv(
    const unsigned short* __restrict__ Xb, const unsigned short* __restrict__ WqT,
    const float* __restrict__ bq, unsigned short* __restrict__ Qb,
    const float* __restrict__ y,
    const unsigned short* __restrict__ WkT, const float* __restrict__ bk2, unsigned short* __restrict__ Kb,
    const unsigned short* __restrict__ WvT, const float* __restrict__ bv2, unsigned short* __restrict__ Vb)
{
    __shared__ __align__(16) unsigned short smem[16384];   // single 32 KB, shared by all paths
    const int id = blockIdx.x;
    if (id < 200) {
        int z = id / 100, rem = id % 100;
        int m0 = (rem / 5) * 128, n0 = (rem % 5) * 128;
        if (z == 0) gemm_body<1, false>(y, WkT, bk2, Kb, 2464, 768, 640, m0, n0, smem);
        else        gemm_body<1, false>(y, WvT, bv2, Vb, 2464, 768, 640, m0, n0, smem);
    } else {
        int orig = id - 200;                       // 0..1279, 1280 % 8 == 0
        int wgid = (orig & 7) * 160 + (orig >> 3); // XCD-chunked bijection
        int m0 = (wgid / 5) * 128, n0 = (wgid % 5) * 128;
        gemm_body<0, false>(Xb, WqT, bq, Qb, 32768, 640, 640, m0, n0, smem);
    }
}

// ---------------- V transpose: Vb [32*77][640] -> Vt [32*8][80][80] (kv 77..79 zeroed) ----------------
__global__ __launch_bounds__(256) void vtrans_kernel(
    const unsigned short* __restrict__ Vb, unsigned short* __restrict__ Vt)
{
    __shared__ unsigned short Vl[77 * 88 + 8];
    const int b = blockIdx.x, h = blockIdx.y;
    const int tid = threadIdx.x;
    for (int idx = tid; idx < 770; idx += 256) {
        int kv = idx / 10, seg = idx % 10;
        *reinterpret_cast<us8*>(&Vl[kv * 88 + seg * 8]) =
            *reinterpret_cast<const us8*>(&Vb[(size_t)(b * 77 + kv) * 640 + h * 80 + seg * 8]);
    }
    __syncthreads();
    unsigned short* out = Vt + (size_t)(b * 8 + h) * 6400;
    for (int idx = tid; idx < 800; idx += 256) {
        int d = idx / 10, seg = idx % 10;
        us8 v;
#pragma unroll
        for (int j = 0; j < 8; ++j) {
            int kv = seg * 8 + j;
            v[j] = (kv < 77) ? Vl[kv * 88 + d] : (unsigned short)0;
        }
        *reinterpret_cast<us8*>(&out[d * 80 + seg * 8]) = v;
    }
}

// ---------------- attention: per (128 q-rows, head, batch) ----------------
__global__ __launch_bounds__(128) void attn_kernel(
    const unsigned short* __restrict__ Q,
    const unsigned short* __restrict__ Kp,   // [2464][640]
    const unsigned short* __restrict__ Vt,   // [256][80][80], kv 77..79 zeroed
    unsigned short* __restrict__ Oa)
{
    __shared__ __align__(16) unsigned short smem[11272];  // P [2][64][88] -> O [128][80]
    const int tid = threadIdx.x, lane = tid & 63, wave = tid >> 6;
    const int l15 = lane & 15, l4 = lane >> 4;
    const int qb = blockIdx.x * 128, h = blockIdx.y, b = blockIdx.z;
    const size_t qrow0 = (size_t)b * SQ_ + qb + wave * 64;
    const size_t kbase = (size_t)b * SKV_ * E_ + h * DH_;
    const size_t vbase = (size_t)(b * 8 + h) * 6400;

    bf16x8 aq[3][4];
#pragma unroll
    for (int ks = 0; ks < 3; ++ks) {
        const int d = ks * 32 + l4 * 8;
#pragma unroll
        for (int m = 0; m < 4; ++m)
            aq[ks][m] = (d < 80) ? lv8(&Q[(qrow0 + m * 16 + l15) * E_ + h * DH_ + d]) : zero8();
    }

    f32x4 accS[4][5];
#pragma unroll
    for (int m = 0; m < 4; ++m)
#pragma unroll
        for (int n = 0; n < 5; ++n)
#pragma unroll
            for (int i = 0; i < 4; ++i) accS[m][n][i] = 0.f;

#pragma unroll
    for (int ks = 0; ks < 3; ++ks) {
        const int d = ks * 32 + l4 * 8;
        bf16x8 bk[5];
#pragma unroll
        for (int n = 0; n < 5; ++n) {
            const int kv = n * 16 + l15;
            bk[n] = (kv < SKV_ && d < 80) ? lv8(&Kp[kbase + (size_t)kv * E_ + d]) : zero8();
        }
        __builtin_amdgcn_s_setprio(1);
#pragma unroll
        for (int n = 0; n < 5; ++n)
#pragma unroll
            for (int m = 0; m < 4; ++m)
                accS[m][n] = __builtin_amdgcn_mfma_f32_16x16x32_bf16(aq[ks][m], bk[n], accS[m][n], 0, 0, 0);
        __builtin_amdgcn_s_setprio(0);
    }

    unsigned short* Pw = smem + wave * 5632;   // [64][88]

    const float scale = 0.11180339887498949f; // 1/sqrt(80)
    float rs[4][4];
#pragma unroll
    for (int m = 0; m < 4; ++m) {
#pragma unroll
        for (int i = 0; i < 4; ++i) {
            float mx = -1e30f;
#pragma unroll
            for (int n = 0; n < 5; ++n) {
                float s = accS[m][n][i] * scale;
                if (n == 4 && l15 >= 13) s = -1e30f;   // kv = 64+l15 >= 77
                accS[m][n][i] = s;
                mx = fmaxf(mx, s);
            }
            mx = fmaxf(mx, __shfl_xor(mx, 1));
            mx = fmaxf(mx, __shfl_xor(mx, 2));
            mx = fmaxf(mx, __shfl_xor(mx, 4));
            mx = fmaxf(mx, __shfl_xor(mx, 8));
            float sum = 0.f;
            const int prow = m * 16 + l4 * 4 + i;
#pragma unroll
            for (int n = 0; n < 5; ++n) {
                float p = __expf(accS[m][n][i] - mx);
                sum += p;
                Pw[prow * 88 + n * 16 + l15] = f2b(p);
            }
            sum += __shfl_xor(sum, 1);
            sum += __shfl_xor(sum, 2);
            sum += __shfl_xor(sum, 4);
            sum += __shfl_xor(sum, 8);
            rs[m][i] = sum;
        }
    }

    f32x4 accO[4][5];
#pragma unroll
    for (int m = 0; m < 4; ++m)
#pragma unroll
        for (int n = 0; n < 5; ++n)
#pragma unroll
            for (int i = 0; i < 4; ++i) accO[m][n][i] = 0.f;

#pragma unroll
    for (int ks = 0; ks < 3; ++ks) {
        const int kv = ks * 32 + l4 * 8;
        bf16x8 ap[4], bv[5];
#pragma unroll
        for (int m = 0; m < 4; ++m)
            ap[m] = (ks < 2 || l4 < 2) ? lv8(&Pw[(m * 16 + l15) * 88 + ks * 32 + l4 * 8])
                                       : zero8();
#pragma unroll
        for (int n = 0; n < 5; ++n) {
            const int d = n * 16 + l15;   // always < 80
            bv[n] = (kv < 80) ? lv8(&Vt[vbase + (size_t)d * 80 + kv]) : zero8();
        }
        __builtin_amdgcn_s_setprio(1);
#pragma unroll
        for (int n = 0; n < 5; ++n)
#pragma unroll
            for (int m = 0; m < 4; ++m)
                accO[m][n] = __builtin_amdgcn_mfma_f32_16x16x32_bf16(ap[m], bv[n], accO[m][n], 0, 0, 0);
        __builtin_amdgcn_s_setprio(0);
    }

    __syncthreads();   // all waves done with P region; becomes O [128][80]
#pragma unroll
    for (int m = 0; m < 4; ++m) {
#pragma unroll
        for (int i = 0; i < 4; ++i) {
            const float inv = 1.f / rs[m][i];
            const int rl = wave * 64 + m * 16 + l4 * 4 + i;
#pragma unroll
            for (int n = 0; n < 5; ++n)
                smem[rl * 80 + n * 16 + l15] = f2b(accO[m][n][i] * inv);
        }
    }
    __syncthreads();
    const size_t obase = (size_t)b * SQ_ + qb;
    for (int idx = tid; idx < 1280; idx += 128) {
        int row = idx / 10, seg = idx % 10;
        *reinterpret_cast<us8*>(&Oa[(obase + row) * E_ + h * DH_ + seg * 8]) =
            *reinterpret_cast<us8*>(&smem[row * 80 + seg * 8]);
    }
}

extern "C" void kernel_launch(void* const* d_in, const int* in_sizes, int n_in,
                              void* d_out, int out_size, void* d_ws, size_t ws_size,
                              hipStream_t stream) {
    const float* x  = (const float*)d_in[0];
    const float* y  = (const float*)d_in[1];
    const float* Wq = (const float*)d_in[2];
    const float* bq = (const float*)d_in[3];
    const float* Wk = (const float*)d_in[4];
    const float* bk = (const float*)d_in[5];
    const float* Wv = (const float*)d_in[6];
    const float* bv = (const float*)d_in[7];
    const float* Wo = (const float*)d_in[8];
    const float* bo = (const float*)d_in[9];
    float* out = (float*)d_out;

    char* ws = (char*)d_ws;
    unsigned short* WqT = (unsigned short*)(ws + 0);         //  819,200 B
    unsigned short* WkT = (unsigned short*)(ws + 819200);    //  983,040 B
    unsigned short* WvT = (unsigned short*)(ws + 1802240);   //  983,040 B
    unsigned short* WoT = (unsigned short*)(ws + 2785280);   //  819,200 B
    unsigned short* Qb  = (unsigned short*)(ws + 3604480);   // 41,943,040 B
    unsigned short* Kb  = (unsigned short*)(ws + 45547520);  //  3,153,920 B
    unsigned short* Vb  = (unsigned short*)(ws + 48701440);  //  3,153,920 B
    unsigned short* Xb  = (unsigned short*)(ws + 51855360);  // 41,943,040 B (dead after fused_qkv)
    unsigned short* Vtb = (unsigned short*)(ws + 51855360);  //  6,553,600 B (aliases Xb)
    // peak footprint: 93,798,400 B (proven available)

    fused_prep<<<3808, 256, 0, stream>>>(Wq, WqT, Wo, WoT, Wk, WkT, Wv, WvT, x, Xb);
    fused_qkv<<<1480, 256, 0, stream>>>(Xb, WqT, bq, Qb, y, WkT, bk, Kb, WvT, bv, Vb);
    vtrans_kernel<<<dim3(32, 8), 256, 0, stream>>>(Vb, Vtb);
    attn_kernel<<<dim3(8, 8, 32), 128, 0, stream>>>(Qb, Kb, Vtb, Qb);
    gemm_o<<<1280, 256, 0, stream>>>(Qb, WoT, bo, out);
}

// Round 9
// 166.385 us; speedup vs baseline: 1.6666x; 1.0490x over previous
//
#include <hip/hip_runtime.h>
#include <hip/hip_bf16.h>

typedef __bf16 bf16x8 __attribute__((ext_vector_type(8)));
typedef float f32x4 __attribute__((ext_vector_type(4)));
typedef unsigned short us8 __attribute__((ext_vector_type(8)));
typedef unsigned int u32x4 __attribute__((ext_vector_type(4)));

#define E_ 640
#define CD_ 768
#define B_ 32
#define SQ_ 1024
#define SKV_ 77
#define H_ 8
#define DH_ 80

typedef __attribute__((address_space(3))) unsigned int as3_u32;
typedef __attribute__((address_space(1))) const unsigned int as1_u32;

__device__ __forceinline__ void gload16(const unsigned short* g, unsigned short* l) {
    __builtin_amdgcn_global_load_lds((as1_u32*)g, (as3_u32*)l, 16, 0, 0);
}
__device__ __forceinline__ void gload16f(const float* g, unsigned short* l) {
    __builtin_amdgcn_global_load_lds((as1_u32*)g, (as3_u32*)l, 16, 0, 0);
}

__device__ __forceinline__ float b2f(unsigned short u) {
    unsigned int x = ((unsigned int)u) << 16;
    return __builtin_bit_cast(float, x);
}
__device__ __forceinline__ unsigned short f2b(float f) {
    unsigned int x = __builtin_bit_cast(unsigned int, f);
    x += 0x7fffu + ((x >> 16) & 1u);   // RNE
    return (unsigned short)(x >> 16);
}
__device__ __forceinline__ bf16x8 lv8(const unsigned short* p) {
    return __builtin_bit_cast(bf16x8, *reinterpret_cast<const us8*>(p));
}
__device__ __forceinline__ bf16x8 zero8() {
    us8 z = {0,0,0,0,0,0,0,0};
    return __builtin_bit_cast(bf16x8, z);
}
__device__ __forceinline__ us8 cvt8(const float* s) {
    f32x4 f0 = *reinterpret_cast<const f32x4*>(s);
    f32x4 f1 = *reinterpret_cast<const f32x4*>(s + 4);
    us8 v;
    v[0]=f2b(f0[0]); v[1]=f2b(f0[1]); v[2]=f2b(f0[2]); v[3]=f2b(f0[3]);
    v[4]=f2b(f1[0]); v[5]=f2b(f1[1]); v[6]=f2b(f1[2]); v[7]=f2b(f1[3]);
    return v;
}
// 8 fp32 -> bf16x8 via v_cvt_pk_bf16_f32 (RNE)
__device__ __forceinline__ bf16x8 cvtpk8(f32x4 lo, f32x4 hi) {
    unsigned int w0, w1, w2, w3;
    asm("v_cvt_pk_bf16_f32 %0, %1, %2" : "=v"(w0) : "v"(lo[0]), "v"(lo[1]));
    asm("v_cvt_pk_bf16_f32 %0, %1, %2" : "=v"(w1) : "v"(lo[2]), "v"(lo[3]));
    asm("v_cvt_pk_bf16_f32 %0, %1, %2" : "=v"(w2) : "v"(hi[0]), "v"(hi[1]));
    asm("v_cvt_pk_bf16_f32 %0, %1, %2" : "=v"(w3) : "v"(hi[2]), "v"(hi[3]));
    u32x4 w = {w0, w1, w2, w3};
    return __builtin_bit_cast(bf16x8, w);
}

// ---------------- fused prep: 4 weight transposes ----------------
__device__ __forceinline__ void transpose_body(
    const float* __restrict__ in, unsigned short* __restrict__ out,
    int K, int N, int bx, int by, unsigned short (*t)[33])
{
    const int tx = threadIdx.x & 31, ty = threadIdx.x >> 5;
    const int n0 = bx * 32, k0 = by * 32;
#pragma unroll
    for (int i = 0; i < 4; ++i)
        t[ty + 8*i][tx] = f2b(in[(size_t)(k0 + ty + 8*i) * N + n0 + tx]);
    __syncthreads();
#pragma unroll
    for (int i = 0; i < 4; ++i)
        out[(size_t)(n0 + ty + 8*i) * K + k0 + tx] = t[tx][ty + 8*i];
}

__global__ __launch_bounds__(256) void fused_prep(
    const float* __restrict__ Wq, unsigned short* __restrict__ WqT,
    const float* __restrict__ Wo, unsigned short* __restrict__ WoT,
    const float* __restrict__ Wk, unsigned short* __restrict__ WkT,
    const float* __restrict__ Wv, unsigned short* __restrict__ WvT)
{
    __shared__ unsigned short t[32][33];
    const int id = blockIdx.x;
    if (id < 800) {                         // Wq / Wo : [640][640]
        int z = id / 400, rem = id % 400;
        transpose_body(z ? Wo : Wq, z ? WoT : WqT, 640, 640, rem % 20, rem / 20, t);
    } else {                                // Wk / Wv : [768][640]
        int id2 = id - 800, z = id2 / 480, rem = id2 % 480;
        transpose_body(z ? Wv : Wk, z ? WvT : WkT, 768, 640, rem % 20, rem / 20, t);
    }
}

// ---------------- GEMM body: C[M][ldc] = A[M][K] @ Wt^T + bias ----------------
// 2-phase double-buffered K-loop. Caller provides the LDS buffer.
// AMODE 0: A bf16, global_load_lds (M % 128 == 0).
// AMODE 1: A fp32, register-staged convert (any M, clamped).
// AMODE 2: A fp32, global_load_lds fp32 + cvt_pk on LDS read, XOR-swizzled (M % 128 == 0).
template<int AMODE, bool CF32>
__device__ __forceinline__ void gemm_body(
    const void* __restrict__ Ap,
    const unsigned short* __restrict__ Wt,
    const float* __restrict__ bias,
    void* __restrict__ Cp,
    int M, int K, int ldc, int m0, int n0,
    unsigned short* smem)
{
    constexpr int BUFSTRIDE = (AMODE == 2) ? 12288 : 8192;   // shorts per buffer pair
    constexpr int AWOFF     = (AMODE == 2) ? 8192 : 4096;    // W offset within buffer
    const int tid = threadIdx.x, lane = tid & 63, wave = tid >> 6;
    const int wr = (wave >> 1) << 6, wc = (wave & 1) << 6;
    const int l15 = lane & 15, l4 = lane >> 4;

    const int cw = wave * 64 + lane;
    const unsigned short* gW0 = Wt + (size_t)(n0 + (cw >> 2)) * K + (cw & 3) * 8;
    const unsigned short* gW1 = Wt + (size_t)(n0 + ((cw + 256) >> 2)) * K + ((cw + 256) & 3) * 8;

    const unsigned short* gA0; const unsigned short* gA1;
    const float* fA0; const float* fA1;
    const float* xbase; int aoff[4];
    if constexpr (AMODE == 0) {
        gA0 = (const unsigned short*)Ap + (size_t)(m0 + (cw >> 2)) * K + (cw & 3) * 8;
        gA1 = (const unsigned short*)Ap + (size_t)(m0 + ((cw + 256) >> 2)) * K + ((cw + 256) & 3) * 8;
    } else if constexpr (AMODE == 1) {
        int c0 = tid, c1 = tid + 256;
        int r0 = m0 + (c0 >> 2); if (r0 >= M) r0 = M - 1;
        int r1 = m0 + (c1 >> 2); if (r1 >= M) r1 = M - 1;
        fA0 = (const float*)Ap + (size_t)r0 * K + (c0 & 3) * 8;
        fA1 = (const float*)Ap + (size_t)r1 * K + (c1 & 3) * 8;
    } else {
        xbase = (const float*)Ap + (size_t)m0 * K;
#pragma unroll
        for (int j = 0; j < 4; ++j) {
            int c = j * 256 + tid;
            int row = c >> 3, sg = (c & 7) ^ (row & 7);   // pre-swizzled source seg
            aoff[j] = row * K + sg * 4;
        }
    }

    f32x4 acc[4][4];
#pragma unroll
    for (int m = 0; m < 4; ++m)
#pragma unroll
        for (int n = 0; n < 4; ++n)
#pragma unroll
            for (int i = 0; i < 4; ++i) acc[m][n][i] = 0.f;

    auto STAGE = [&](int buf) {
        unsigned short* As = smem + buf * BUFSTRIDE;
        unsigned short* Ws = As + AWOFF;
        if constexpr (AMODE == 0) {
            gload16(gA0, As + cw * 8);
            gload16(gA1, As + (cw + 256) * 8);
            gA0 += 32; gA1 += 32;
        } else if constexpr (AMODE == 1) {
            *reinterpret_cast<us8*>(As + tid * 8) = cvt8(fA0);
            *reinterpret_cast<us8*>(As + (tid + 256) * 8) = cvt8(fA1);
            fA0 += 32; fA1 += 32;
        } else {
#pragma unroll
            for (int j = 0; j < 4; ++j)
                gload16f(xbase + aoff[j], As + (j * 256 + tid) * 8);
            xbase += 32;
        }
        gload16(gW0, Ws + cw * 8);
        gload16(gW1, Ws + (cw + 256) * 8);
        gW0 += 32; gW1 += 32;
    };
    auto COMPUTE = [&](int buf) {
        const unsigned short* As = smem + buf * BUFSTRIDE;
        const unsigned short* Ws = As + AWOFF;
        bf16x8 a[4], b[4];
        if constexpr (AMODE == 2) {
            const float* Af = (const float*)As;
#pragma unroll
            for (int m = 0; m < 4; ++m) {
                const int row = wr + m * 16 + l15;
                const int t0 = (l4 * 2) ^ (row & 7);
                const int t1 = (l4 * 2 + 1) ^ (row & 7);
                f32x4 lo = *reinterpret_cast<const f32x4*>(Af + row * 32 + t0 * 4);
                f32x4 hi = *reinterpret_cast<const f32x4*>(Af + row * 32 + t1 * 4);
                a[m] = cvtpk8(lo, hi);
            }
        } else {
#pragma unroll
            for (int m = 0; m < 4; ++m)
                a[m] = lv8(&As[(wr + m * 16 + l15) * 32 + l4 * 8]);
        }
#pragma unroll
        for (int n = 0; n < 4; ++n)
            b[n] = lv8(&Ws[(wc + n * 16 + l15) * 32 + l4 * 8]);
        __builtin_amdgcn_s_setprio(1);
#pragma unroll
        for (int m = 0; m < 4; ++m)
#pragma unroll
            for (int n = 0; n < 4; ++n)
                acc[m][n] = __builtin_amdgcn_mfma_f32_16x16x32_bf16(a[m], b[n], acc[m][n], 0, 0, 0);
        __builtin_amdgcn_s_setprio(0);
    };

    const int nk = K >> 5;   // 20 or 24, always even and >= 4
    STAGE(0);
    __syncthreads();
    for (int kt = 0; kt < nk - 2; kt += 2) {
        STAGE(1);
        COMPUTE(0);
        __syncthreads();
        STAGE(0);
        COMPUTE(1);
        __syncthreads();
    }
    STAGE(1);
    COMPUTE(0);
    __syncthreads();
    COMPUTE(1);

    float bs[4];
#pragma unroll
    for (int n = 0; n < 4; ++n) bs[n] = bias[n0 + wc + n * 16 + l15];

    if constexpr (CF32) {
        float* C = (float*)Cp;
        float* fs = (float*)smem;
#pragma unroll
        for (int p = 0; p < 2; ++p) {
            __syncthreads();
            if (wr == p * 64) {
#pragma unroll
                for (int m = 0; m < 4; ++m)
#pragma unroll
                    for (int n = 0; n < 4; ++n)
#pragma unroll
                        for (int i = 0; i < 4; ++i)
                            fs[(m * 16 + l4 * 4 + i) * 128 + wc + n * 16 + l15] =
                                acc[m][n][i] + bs[n];
            }
            __syncthreads();
#pragma unroll
            for (int r = 0; r < 8; ++r) {
                const int off = (r * 256 + tid) * 4;
                const int row = off >> 7, col = off & 127;
                const int grow = m0 + p * 64 + row;
                if (grow < M)
                    *reinterpret_cast<f32x4*>(&C[(size_t)grow * ldc + n0 + col]) =
                        *reinterpret_cast<const f32x4*>(&fs[off]);
            }
        }
    } else {
        unsigned short* C = (unsigned short*)Cp;
#pragma unroll
        for (int p = 0; p < 2; ++p) {
            __syncthreads();
            if (wr == p * 64) {
#pragma unroll
                for (int m = 0; m < 4; ++m)
#pragma unroll
                    for (int n = 0; n < 4; ++n)
#pragma unroll
                        for (int i = 0; i < 4; ++i)
                            smem[(m * 16 + l4 * 4 + i) * 128 + wc + n * 16 + l15] =
                                f2b(acc[m][n][i] + bs[n]);
            }
            __syncthreads();
#pragma unroll
            for (int r = 0; r < 4; ++r) {
                const int off = (r * 256 + tid) * 8;
                const int row = off >> 7, col = off & 127;
                const int grow = m0 + p * 64 + row;
                if (grow < M)
                    *reinterpret_cast<us8*>(&C[(size_t)grow * ldc + n0 + col]) =
                        *reinterpret_cast<us8*>(&smem[off]);
            }
        }
    }
}

// ---------------- O-proj: 1-D grid with XCD-chunked swizzle (1280 % 8 == 0) ----------------
__global__ __launch_bounds__(256) void gemm_o(
    const unsigned short* __restrict__ Ap, const unsigned short* __restrict__ Wt,
    const float* __restrict__ bias, float* __restrict__ Cp)
{
    __shared__ __align__(16) unsigned short smem[16384];
    const int orig = blockIdx.x;
    const int wgid = (orig & 7) * 160 + (orig >> 3);
    gemm_body<0, true>(Ap, Wt, bias, Cp, 32768, 640, 640, (wgid / 5) * 128, (wgid % 5) * 128, smem);
}

// ---------------- fused Q-proj (fp32 x, AMODE2) + K/V-proj (fp32 y, AMODE1) ----------------
// blocks [0,200): KV; blocks [200, 1480): Q with XCD swizzle
__global__ __launch_bounds__(256) void fused_qkv(
    const float* __restrict__ x, const unsigned short* __restrict__ WqT,
    const float* __restrict__ bq, unsigned short* __restrict__ Qb,
    const float* __restrict__ y,
    const unsigned short* __restrict__ WkT, const float* __restrict__ bk2, unsigned short* __restrict__ Kb,
    const unsigned short* __restrict__ WvT, const float* __restrict__ bv2, unsigned short* __restrict__ Vb)
{
    __shared__ __align__(16) unsigned short smem[24576];   // 48 KB shared by all paths
    const int id = blockIdx.x;
    if (id < 200) {
        int z = id / 100, rem = id % 100;
        int m0 = (rem / 5) * 128, n0 = (rem % 5) * 128;
        if (z == 0) gemm_body<1, false>(y, WkT, bk2, Kb, 2464, 768, 640, m0, n0, smem);
        else        gemm_body<1, false>(y, WvT, bv2, Vb, 2464, 768, 640, m0, n0, smem);
    } else {
        int orig = id - 200;                       // 0..1279, 1280 % 8 == 0
        int wgid = (orig & 7) * 160 + (orig >> 3); // XCD-chunked bijection
        int m0 = (wgid / 5) * 128, n0 = (wgid % 5) * 128;
        gemm_body<2, false>(x, WqT, bq, Qb, 32768, 640, 640, m0, n0, smem);
    }
}

// ---------------- V transpose: Vb [32*77][640] -> Vt [32*8][80][80] (kv 77..79 zeroed) ----------------
__global__ __launch_bounds__(256) void vtrans_kernel(
    const unsigned short* __restrict__ Vb, unsigned short* __restrict__ Vt)
{
    __shared__ unsigned short Vl[77 * 88 + 8];
    const int b = blockIdx.x, h = blockIdx.y;
    const int tid = threadIdx.x;
    for (int idx = tid; idx < 770; idx += 256) {
        int kv = idx / 10, seg = idx % 10;
        *reinterpret_cast<us8*>(&Vl[kv * 88 + seg * 8]) =
            *reinterpret_cast<const us8*>(&Vb[(size_t)(b * 77 + kv) * 640 + h * 80 + seg * 8]);
    }
    __syncthreads();
    unsigned short* out = Vt + (size_t)(b * 8 + h) * 6400;
    for (int idx = tid; idx < 800; idx += 256) {
        int d = idx / 10, seg = idx % 10;
        us8 v;
#pragma unroll
        for (int j = 0; j < 8; ++j) {
            int kv = seg * 8 + j;
            v[j] = (kv < 77) ? Vl[kv * 88 + d] : (unsigned short)0;
        }
        *reinterpret_cast<us8*>(&out[d * 80 + seg * 8]) = v;
    }
}

// ---------------- attention: per (128 q-rows, head, batch) ----------------
__global__ __launch_bounds__(128) void attn_kernel(
    const unsigned short* __restrict__ Q,
    const unsigned short* __restrict__ Kp,   // [2464][640]
    const unsigned short* __restrict__ Vt,   // [256][80][80], kv 77..79 zeroed
    unsigned short* __restrict__ Oa)
{
    __shared__ __align__(16) unsigned short smem[11272];  // P [2][64][88] -> O [128][80]
    const int tid = threadIdx.x, lane = tid & 63, wave = tid >> 6;
    const int l15 = lane & 15, l4 = lane >> 4;
    const int qb = blockIdx.x * 128, h = blockIdx.y, b = blockIdx.z;
    const size_t qrow0 = (size_t)b * SQ_ + qb + wave * 64;
    const size_t kbase = (size_t)b * SKV_ * E_ + h * DH_;
    const size_t vbase = (size_t)(b * 8 + h) * 6400;

    bf16x8 aq[3][4];
#pragma unroll
    for (int ks = 0; ks < 3; ++ks) {
        const int d = ks * 32 + l4 * 8;
#pragma unroll
        for (int m = 0; m < 4; ++m)
            aq[ks][m] = (d < 80) ? lv8(&Q[(qrow0 + m * 16 + l15) * E_ + h * DH_ + d]) : zero8();
    }

    f32x4 accS[4][5];
#pragma unroll
    for (int m = 0; m < 4; ++m)
#pragma unroll
        for (int n = 0; n < 5; ++n)
#pragma unroll
            for (int i = 0; i < 4; ++i) accS[m][n][i] = 0.f;

#pragma unroll
    for (int ks = 0; ks < 3; ++ks) {
        const int d = ks * 32 + l4 * 8;
        bf16x8 bk[5];
#pragma unroll
        for (int n = 0; n < 5; ++n) {
            const int kv = n * 16 + l15;
            bk[n] = (kv < SKV_ && d < 80) ? lv8(&Kp[kbase + (size_t)kv * E_ + d]) : zero8();
        }
        __builtin_amdgcn_s_setprio(1);
#pragma unroll
        for (int n = 0; n < 5; ++n)
#pragma unroll
            for (int m = 0; m < 4; ++m)
                accS[m][n] = __builtin_amdgcn_mfma_f32_16x16x32_bf16(aq[ks][m], bk[n], accS[m][n], 0, 0, 0);
        __builtin_amdgcn_s_setprio(0);
    }

    unsigned short* Pw = smem + wave * 5632;   // [64][88]

    const float scale = 0.11180339887498949f; // 1/sqrt(80)
    float rs[4][4];
#pragma unroll
    for (int m = 0; m < 4; ++m) {
#pragma unroll
        for (int i = 0; i < 4; ++i) {
            float mx = -1e30f;
#pragma unroll
            for (int n = 0; n < 5; ++n) {
                float s = accS[m][n][i] * scale;
                if (n == 4 && l15 >= 13) s = -1e30f;   // kv = 64+l15 >= 77
                accS[m][n][i] = s;
                mx = fmaxf(mx, s);
            }
            mx = fmaxf(mx, __shfl_xor(mx, 1));
            mx = fmaxf(mx, __shfl_xor(mx, 2));
            mx = fmaxf(mx, __shfl_xor(mx, 4));
            mx = fmaxf(mx, __shfl_xor(mx, 8));
            float sum = 0.f;
            const int prow = m * 16 + l4 * 4 + i;
#pragma unroll
            for (int n = 0; n < 5; ++n) {
                float p = __expf(accS[m][n][i] - mx);
                sum += p;
                Pw[prow * 88 + n * 16 + l15] = f2b(p);
            }
            sum += __shfl_xor(sum, 1);
            sum += __shfl_xor(sum, 2);
            sum += __shfl_xor(sum, 4);
            sum += __shfl_xor(sum, 8);
            rs[m][i] = sum;
        }
    }

    f32x4 accO[4][5];
#pragma unroll
    for (int m = 0; m < 4; ++m)
#pragma unroll
        for (int n = 0; n < 5; ++n)
#pragma unroll
            for (int i = 0; i < 4; ++i) accO[m][n][i] = 0.f;

#pragma unroll
    for (int ks = 0; ks < 3; ++ks) {
        const int kv = ks * 32 + l4 * 8;
        bf16x8 ap[4], bv[5];
#pragma unroll
        for (int m = 0; m < 4; ++m)
            ap[m] = (ks < 2 || l4 < 2) ? lv8(&Pw[(m * 16 + l15) * 88 + ks * 32 + l4 * 8])
                                       : zero8();
#pragma unroll
        for (int n = 0; n < 5; ++n) {
            const int d = n * 16 + l15;   // always < 80
            bv[n] = (kv < 80) ? lv8(&Vt[vbase + (size_t)d * 80 + kv]) : zero8();
        }
        __builtin_amdgcn_s_setprio(1);
#pragma unroll
        for (int n = 0; n < 5; ++n)
#pragma unroll
            for (int m = 0; m < 4; ++m)
                accO[m][n] = __builtin_amdgcn_mfma_f32_16x16x32_bf16(ap[m], bv[n], accO[m][n], 0, 0, 0);
        __builtin_amdgcn_s_setprio(0);
    }

    __syncthreads();   // all waves done with P region; becomes O [128][80]
#pragma unroll
    for (int m = 0; m < 4; ++m) {
#pragma unroll
        for (int i = 0; i < 4; ++i) {
            const float inv = 1.f / rs[m][i];
            const int rl = wave * 64 + m * 16 + l4 * 4 + i;
#pragma unroll
            for (int n = 0; n < 5; ++n)
                smem[rl * 80 + n * 16 + l15] = f2b(accO[m][n][i] * inv);
        }
    }
    __syncthreads();
    const size_t obase = (size_t)b * SQ_ + qb;
    for (int idx = tid; idx < 1280; idx += 128) {
        int row = idx / 10, seg = idx % 10;
        *reinterpret_cast<us8*>(&Oa[(obase + row) * E_ + h * DH_ + seg * 8]) =
            *reinterpret_cast<us8*>(&smem[row * 80 + seg * 8]);
    }
}

extern "C" void kernel_launch(void* const* d_in, const int* in_sizes, int n_in,
                              void* d_out, int out_size, void* d_ws, size_t ws_size,
                              hipStream_t stream) {
    const float* x  = (const float*)d_in[0];
    const float* y  = (const float*)d_in[1];
    const float* Wq = (const float*)d_in[2];
    const float* bq = (const float*)d_in[3];
    const float* Wk = (const float*)d_in[4];
    const float* bk = (const float*)d_in[5];
    const float* Wv = (const float*)d_in[6];
    const float* bv = (const float*)d_in[7];
    const float* Wo = (const float*)d_in[8];
    const float* bo = (const float*)d_in[9];
    float* out = (float*)d_out;

    char* ws = (char*)d_ws;
    unsigned short* WqT = (unsigned short*)(ws + 0);         //  819,200 B
    unsigned short* WkT = (unsigned short*)(ws + 819200);    //  983,040 B
    unsigned short* WvT = (unsigned short*)(ws + 1802240);   //  983,040 B
    unsigned short* WoT = (unsigned short*)(ws + 2785280);   //  819,200 B
    unsigned short* Qb  = (unsigned short*)(ws + 3604480);   // 41,943,040 B
    unsigned short* Kb  = (unsigned short*)(ws + 45547520);  //  3,153,920 B
    unsigned short* Vb  = (unsigned short*)(ws + 48701440);  //  3,153,920 B
    unsigned short* Vtb = (unsigned short*)(ws + 51855360);  //  6,553,600 B
    // footprint: 58,408,960 B (well under the proven 93.8 MB)

    fused_prep<<<1760, 256, 0, stream>>>(Wq, WqT, Wo, WoT, Wk, WkT, Wv, WvT);
    fused_qkv<<<1480, 256, 0, stream>>>(x, WqT, bq, Qb, y, WkT, bk, Kb, WvT, bv, Vb);
    vtrans_kernel<<<dim3(32, 8), 256, 0, stream>>>(Vb, Vtb);
    attn_kernel<<<dim3(8, 8, 32), 128, 0, stream>>>(Qb, Kb, Vtb, Qb);
    gemm_o<<<1280, 256, 0, stream>>>(Qb, WoT, bo, out);
}